// Round 2
// baseline (3297.129 us; speedup 1.0000x reference)
//
#include <hip/hip_runtime.h>

// GIN encoder: N=100k nodes, E=3.2M edges, G=512 graphs, H=64, L=3.
// Round 2: replace CSR build (fill_csr was 285us with 16x write amplification)
// with bucketed edge partition: bucket = dst>>7 (128 nodes/bucket), fixed
// capacity CAP edges/bucket. Block-staged scatter gives contiguous write runs.
// Aggregation: one block per bucket, 32KB LDS accumulator + LDS float atomics.
// Fusions: BN stats into MLP epilogue; BN finalize into BN apply; BN apply +
// pool for last layer. 12 launches total.

#define HD 64
#define NBMAX 1024       // max buckets (N <= 131072)
#define CAP 4608         // bucket capacity; Poisson(4096), 8 sigma margin
#define CHUNK 8192       // edges per scatter block

// ---- bucketed edge scatter: bucketed[b*CAP + r] = src | (dstLocal<<20) ----
__global__ __launch_bounds__(256) void bucket_scatter(
    const int* __restrict__ src, const int* __restrict__ dst,
    int* __restrict__ cursor, int* __restrict__ bucketed, int E) {
    __shared__ int h[NBMAX];
    __shared__ int base[NBMAX];
    int t = threadIdx.x;
    for (int i = t; i < NBMAX; i += 256) h[i] = 0;
    __syncthreads();
    int e0 = blockIdx.x * CHUNK, e1 = min(e0 + CHUNK, E);
    for (int e = e0 + t; e < e1; e += 256) atomicAdd(&h[dst[e] >> 7], 1);
    __syncthreads();
    for (int i = t; i < NBMAX; i += 256) {
        int v = h[i];
        base[i] = v ? atomicAdd(&cursor[i], v) : 0;
        h[i] = 0;  // reuse as intra-block rank counter
    }
    __syncthreads();
    for (int e = e0 + t; e < e1; e += 256) {
        int d = dst[e];
        int bk = d >> 7;
        int r = base[bk] + atomicAdd(&h[bk], 1);
        if (r < CAP) bucketed[bk * CAP + r] = src[e] | ((d & 127) << 20);
    }
}

// ---- layer-0 aggregation (d=3): LDS accumulator per bucket ----
__global__ __launch_bounds__(256) void agg3_b(
    const float* __restrict__ x, const int* __restrict__ bucketed,
    const int* __restrict__ bcnt, float* __restrict__ out, int N) {
    __shared__ float acc[128 * 3];
    int b = blockIdx.x, t = threadIdx.x, node0 = b << 7;
    for (int i = t; i < 384; i += 256) {
        int n = node0 + i / 3;
        acc[i] = (n < N) ? x[n * 3 + i % 3] : 0.f;  // self term
    }
    __syncthreads();
    int s = b * CAP, cnt = min(bcnt[b], CAP);
    for (int j = t; j < cnt; j += 256) {
        int p = bucketed[s + j];
        int srcn = p & 0xFFFFF;
        int row = p >> 20;
        atomicAdd(&acc[row * 3 + 0], x[srcn * 3 + 0]);
        atomicAdd(&acc[row * 3 + 1], x[srcn * 3 + 1]);
        atomicAdd(&acc[row * 3 + 2], x[srcn * 3 + 2]);
    }
    __syncthreads();
    for (int i = t; i < 384; i += 256) {
        int n = node0 + i / 3;
        if (n < N) out[n * 3 + i % 3] = acc[i];
    }
}

// ---- layers 1-2 aggregation (d=64): 32 lanes/edge, lane l owns floats l,l+32
// -> LDS atomic banks cover all 32 (conflict-free); global reads 128B runs ----
__global__ __launch_bounds__(256) void agg_b(
    const float* __restrict__ x, const int* __restrict__ bucketed,
    const int* __restrict__ bcnt, float* __restrict__ out, int N) {
    __shared__ float acc[128 * 64];  // 32KB
    int b = blockIdx.x, t = threadIdx.x, node0 = b << 7;
    const float4* xr = (const float4*)x;
    for (int i = t; i < 2048; i += 256) {
        int n = node0 + (i >> 4);
        ((float4*)acc)[i] = (n < N) ? xr[n * 16 + (i & 15)]
                                    : make_float4(0.f, 0.f, 0.f, 0.f);
    }
    __syncthreads();
    int s = b * CAP, cnt = min(bcnt[b], CAP);
    int g = t >> 5, l = t & 31;  // 8 groups of 32 lanes
    for (int j = g; j < cnt; j += 8) {
        int p = bucketed[s + j];
        int srcn = p & 0xFFFFF;
        int row = p >> 20;
        float v0 = x[srcn * 64 + l];
        float v1 = x[srcn * 64 + l + 32];
        float* bp = acc + row * 64;
        atomicAdd(bp + l, v0);
        atomicAdd(bp + l + 32, v1);
    }
    __syncthreads();
    for (int i = t; i < 2048; i += 256) {
        int n = node0 + (i >> 4);
        if (n < N) ((float4*)out)[n * 16 + (i & 15)] = ((const float4*)acc)[i];
    }
}

// ---- MLP: hout = relu(hin@W1+b1)@W2+b2, + fused BN sum/sumsq accumulation ----
__global__ __launch_bounds__(256) void mlp64(
    const float* __restrict__ hin, float* __restrict__ hout,
    const float* __restrict__ W1, const float* __restrict__ b1,
    const float* __restrict__ W2, const float* __restrict__ b2,
    float* __restrict__ bnsum, float* __restrict__ bnsq,
    int kin, int N) {
    __shared__ __align__(16) float w1s[64 * 64];
    __shared__ __align__(16) float w2s[64 * 64];
    __shared__ float b1s[64], b2s[64];
    __shared__ float hp[16][68];  // +4 pad
    __shared__ float ts[16][68];
    int t = threadIdx.x;
    for (int i = t; i < kin * 64; i += 256) w1s[i] = W1[i];
    for (int i = t; i < 64 * 64; i += 256) w2s[i] = W2[i];
    if (t < 64) { b1s[t] = b1[t]; b2s[t] = b2[t]; }
    __syncthreads();
    int g = t >> 4, l = t & 15, f0 = l * 4;
    float s0 = 0.f, s1 = 0.f, s2 = 0.f, s3 = 0.f;
    float q0 = 0.f, q1 = 0.f, q2 = 0.f, q3 = 0.f;
    // grid=1250: 20000 nodes/sweep, 100000/20000 = 5 exact iters, no tail
    for (int n = blockIdx.x * 16 + g; n < N; n += gridDim.x * 16) {
        for (int k = l; k < kin; k += 16) hp[g][k] = hin[n * kin + k];
        __syncthreads();
        float a0 = b1s[f0], a1 = b1s[f0 + 1], a2 = b1s[f0 + 2], a3 = b1s[f0 + 3];
        for (int k = 0; k < kin; k++) {
            float h = hp[g][k];
            float4 w = *(const float4*)&w1s[k * 64 + f0];
            a0 += h * w.x; a1 += h * w.y; a2 += h * w.z; a3 += h * w.w;
        }
        ts[g][f0] = fmaxf(a0, 0.f);
        ts[g][f0 + 1] = fmaxf(a1, 0.f);
        ts[g][f0 + 2] = fmaxf(a2, 0.f);
        ts[g][f0 + 3] = fmaxf(a3, 0.f);
        __syncthreads();
        a0 = b2s[f0]; a1 = b2s[f0 + 1]; a2 = b2s[f0 + 2]; a3 = b2s[f0 + 3];
        for (int k = 0; k < 64; k++) {
            float h = ts[g][k];
            float4 w = *(const float4*)&w2s[k * 64 + f0];
            a0 += h * w.x; a1 += h * w.y; a2 += h * w.z; a3 += h * w.w;
        }
        float4 o; o.x = a0; o.y = a1; o.z = a2; o.w = a3;
        ((float4*)hout)[n * 16 + l] = o;
        s0 += a0; s1 += a1; s2 += a2; s3 += a3;
        q0 += a0 * a0; q1 += a1 * a1; q2 += a2 * a2; q3 += a3 * a3;
        __syncthreads();  // protect hp/ts reuse
    }
    // block-reduce BN partials (reuse hp/ts; loop exit is block-uniform)
    __syncthreads();
    hp[g][f0] = s0; hp[g][f0 + 1] = s1; hp[g][f0 + 2] = s2; hp[g][f0 + 3] = s3;
    ts[g][f0] = q0; ts[g][f0 + 1] = q1; ts[g][f0 + 2] = q2; ts[g][f0 + 3] = q3;
    __syncthreads();
    if (t < 64) {
        float S = 0.f, Q = 0.f;
        for (int g2 = 0; g2 < 16; g2++) { S += hp[g2][t]; Q += ts[g2][t]; }
        atomicAdd(&bnsum[t], S);
        atomicAdd(&bnsq[t], Q);
    }
}

// ---- BN finalize + apply + ReLU (in place) ----
__global__ void bn_apply(float* __restrict__ h, const float* __restrict__ bnsum,
                         const float* __restrict__ bnsq, const float* __restrict__ gamma,
                         const float* __restrict__ beta, int N) {
    __shared__ float sc[64], sh[64];
    int t = threadIdx.x;
    if (t < 64) {
        float mu = bnsum[t] / (float)N;
        float var = bnsq[t] / (float)N - mu * mu;
        float s = gamma[t] * rsqrtf(var + 1e-5f);
        sc[t] = s;
        sh[t] = beta[t] - mu * s;
    }
    __syncthreads();
    int idx = blockIdx.x * 256 + t;
    if (idx >= N * 16) return;
    int f0 = (idx & 15) * 4;
    float4 v = ((float4*)h)[idx];
    v.x = fmaxf(v.x * sc[f0] + sh[f0], 0.f);
    v.y = fmaxf(v.y * sc[f0 + 1] + sh[f0 + 1], 0.f);
    v.z = fmaxf(v.z * sc[f0 + 2] + sh[f0 + 2], 0.f);
    v.w = fmaxf(v.w * sc[f0 + 3] + sh[f0 + 3], 0.f);
    ((float4*)h)[idx] = v;
}

// ---- last layer: BN finalize + apply + ReLU + pool atomics (no x writeback) ----
__global__ void bn_apply_pool(const float* __restrict__ h, const int* __restrict__ batch,
                              const float* __restrict__ bnsum, const float* __restrict__ bnsq,
                              const float* __restrict__ gamma, const float* __restrict__ beta,
                              float* __restrict__ pool, float* __restrict__ cnt, int N) {
    __shared__ float sc[64], sh[64];
    int t = threadIdx.x;
    if (t < 64) {
        float mu = bnsum[t] / (float)N;
        float var = bnsq[t] / (float)N - mu * mu;
        float s = gamma[t] * rsqrtf(var + 1e-5f);
        sc[t] = s;
        sh[t] = beta[t] - mu * s;
    }
    __syncthreads();
    int idx = blockIdx.x * 256 + t;
    if (idx >= N * 16) return;
    int n = idx >> 4, l = idx & 15, f0 = l * 4;
    int bg = batch[n];
    float4 v = ((const float4*)h)[idx];
    v.x = fmaxf(v.x * sc[f0] + sh[f0], 0.f);
    v.y = fmaxf(v.y * sc[f0 + 1] + sh[f0 + 1], 0.f);
    v.z = fmaxf(v.z * sc[f0 + 2] + sh[f0 + 2], 0.f);
    v.w = fmaxf(v.w * sc[f0 + 3] + sh[f0 + 3], 0.f);
    float* pp = &pool[bg * 64 + f0];
    atomicAdd(pp + 0, v.x);
    atomicAdd(pp + 1, v.y);
    atomicAdd(pp + 2, v.z);
    atomicAdd(pp + 3, v.w);
    if (l == 0) atomicAdd(&cnt[bg], 1.0f);
}

__global__ void final_out(const float* __restrict__ pool, const float* __restrict__ cnt,
                          const float* __restrict__ wout, const float* __restrict__ bout,
                          float* __restrict__ out) {
    __shared__ float gr[64];
    int g = blockIdx.x, t = threadIdx.x;
    float c = cnt[g];
    float v = pool[g * 64 + t];
    gr[t] = (c > 0.f) ? v / fmaxf(c, 1.f) : 0.f;
    __syncthreads();
    float acc = bout[t];
    for (int f = 0; f < 64; f++) acc += gr[f] * wout[f * 64 + t];
    out[g * 64 + t] = acc;
}

extern "C" void kernel_launch(void* const* d_in, const int* in_sizes, int n_in,
                              void* d_out, int out_size, void* d_ws, size_t ws_size,
                              hipStream_t stream) {
    const float* x     = (const float*)d_in[0];
    const int*   ei    = (const int*)d_in[1];
    const int*   batch = (const int*)d_in[2];
    const float* w1_0  = (const float*)d_in[3];
    const float* w1_r  = (const float*)d_in[4];
    const float* b1    = (const float*)d_in[5];
    const float* w2    = (const float*)d_in[6];
    const float* b2    = (const float*)d_in[7];
    const float* gamma = (const float*)d_in[8];
    const float* beta  = (const float*)d_in[9];
    const float* wout  = (const float*)d_in[10];
    const float* bout  = (const float*)d_in[11];
    float* out = (float*)d_out;

    const int N = in_sizes[2];      // 100000
    const int E = in_sizes[1] / 2;  // 3200000
    const int G = out_size / HD;    // 512
    const int NB = (N + 127) >> 7;  // 782 buckets

    // Workspace layout (~66 MB)
    float* bufA = (float*)d_ws;                 // N*64
    float* bufB = bufA + (size_t)N * 64;        // N*64 (also holds h3 for layer0)
    // contiguous zero region:
    int*   cursor  = (int*)(bufB + (size_t)N * 64);  // NBMAX ints
    float* bnstats = (float*)(cursor + NBMAX);       // 6*64 (layer i: sum@i*128, sq@i*128+64)
    float* pool    = bnstats + 384;                  // G*64
    float* cnt     = pool + (size_t)G * 64;          // G
    int*   bucketed = (int*)(cnt + G);               // NB*CAP ints (~14.4 MB)

    const int* srcv = ei;
    const int* dstv = ei + E;

    size_t zero_bytes = (NBMAX + 384 + (size_t)G * 64 + G) * 4;
    hipMemsetAsync(cursor, 0, zero_bytes, stream);

    bucket_scatter<<<(E + CHUNK - 1) / CHUNK, 256, 0, stream>>>(srcv, dstv, cursor, bucketed, E);

    // --- Layer 0 (kin=3) ---
    agg3_b<<<NB, 256, 0, stream>>>(x, bucketed, cursor, bufB, N);
    mlp64<<<1250, 256, 0, stream>>>(bufB, bufA, w1_0, b1, w2, b2,
                                    bnstats, bnstats + 64, 3, N);
    bn_apply<<<(N * 16 + 255) / 256, 256, 0, stream>>>(bufA, bnstats, bnstats + 64,
                                                       gamma, beta, N);

    // --- Layer 1 ---
    agg_b<<<NB, 256, 0, stream>>>(bufA, bucketed, cursor, bufB, N);
    mlp64<<<1250, 256, 0, stream>>>(bufB, bufA, w1_r, b1 + 64, w2 + 4096, b2 + 64,
                                    bnstats + 128, bnstats + 192, 64, N);
    bn_apply<<<(N * 16 + 255) / 256, 256, 0, stream>>>(bufA, bnstats + 128, bnstats + 192,
                                                       gamma + 64, beta + 64, N);

    // --- Layer 2 (BN apply fused with pool) ---
    agg_b<<<NB, 256, 0, stream>>>(bufA, bucketed, cursor, bufB, N);
    mlp64<<<1250, 256, 0, stream>>>(bufB, bufA, w1_r + 4096, b1 + 128, w2 + 8192, b2 + 128,
                                    bnstats + 256, bnstats + 320, 64, N);
    bn_apply_pool<<<(N * 16 + 255) / 256, 256, 0, stream>>>(bufA, batch,
                                                            bnstats + 256, bnstats + 320,
                                                            gamma + 128, beta + 128,
                                                            pool, cnt, N);

    final_out<<<G, 64, 0, stream>>>(pool, cnt, wout, bout, out);
}

// Round 3
// 858.589 us; speedup vs baseline: 3.8402x; 3.8402x over previous
//
#include <hip/hip_runtime.h>

// GIN encoder: N=100k nodes, E=3.2M edges, G=512 graphs, H=64, L=3.
// Round 3: NO float atomics in hot paths (they compile to CAS loops -> round-2
// disaster). CSR build via bucket scatter (bucket = dst>>7) + per-bucket LDS
// counting sort (int atomics only, coalesced writeback) -> exact CSR in
// bucketed layout. Aggregation = round-1-style pure gather (16 lanes/node,
// float4). MLP keeps fused BN-stats epilogue.

#define HD 64
#define NBMAX 1024       // max buckets (N <= 131072)
#define CAP 4608         // bucket capacity; mean 4092, ~8 sigma margin
#define CHUNK 8192       // edges per scatter block

// ---- stage 1: bucketed[b*CAP + r] = src | (dstLocal<<20), contiguous runs ----
__global__ __launch_bounds__(256) void bucket_scatter(
    const int* __restrict__ src, const int* __restrict__ dst,
    int* __restrict__ cursor, int* __restrict__ bucketed, int E) {
    __shared__ int h[NBMAX];
    __shared__ int base[NBMAX];
    int t = threadIdx.x;
    for (int i = t; i < NBMAX; i += 256) h[i] = 0;
    __syncthreads();
    int e0 = blockIdx.x * CHUNK, e1 = min(e0 + CHUNK, E);
    for (int e = e0 + t; e < e1; e += 256) atomicAdd(&h[dst[e] >> 7], 1);
    __syncthreads();
    for (int i = t; i < NBMAX; i += 256) {
        int v = h[i];
        base[i] = v ? atomicAdd(&cursor[i], v) : 0;
        h[i] = 0;  // reuse as intra-block rank counter
    }
    __syncthreads();
    for (int e = e0 + t; e < e1; e += 256) {
        int d = dst[e];
        int bk = d >> 7;
        int r = base[bk] + atomicAdd(&h[bk], 1);
        if (r < CAP) bucketed[bk * CAP + r] = src[e] | ((d & 127) << 20);
    }
}

// ---- stage 2: per-bucket counting sort -> CSR (in place), rowstart/rowend ----
__global__ __launch_bounds__(256) void bucket_csr(
    int* __restrict__ bucketed, const int* __restrict__ bcnt,
    int* __restrict__ rowstart, int* __restrict__ rowend, int N) {
    __shared__ int ein[CAP];
    __shared__ int eout[CAP];
    __shared__ int hist[128];
    __shared__ int base[129];
    int b = blockIdx.x, t = threadIdx.x;
    int s = b * CAP, node0 = b << 7;
    int cnt = min(bcnt[b], CAP);
    if (t < 128) hist[t] = 0;
    __syncthreads();
    for (int j = t; j < cnt; j += 256) {
        int p = bucketed[s + j];
        ein[j] = p;
        atomicAdd(&hist[p >> 20], 1);
    }
    __syncthreads();
    // exclusive scan hist -> base[0..128]
    if (t < 128) base[t + 1] = hist[t];
    if (t == 0) base[0] = 0;
    __syncthreads();
    for (int off = 1; off < 128; off <<= 1) {
        int v = 0;
        if (t < 128 && (t + 1) > off) v = base[t + 1 - off];
        __syncthreads();
        if (t < 128 && (t + 1) > off) base[t + 1] += v;
        __syncthreads();
    }
    if (t < 128) {
        int n = node0 + t;
        if (n < N) {
            rowstart[n] = s + base[t];
            rowend[n] = s + base[t + 1];
        }
        hist[t] = 0;  // reuse as per-row cursor
    }
    __syncthreads();
    for (int j = t; j < cnt; j += 256) {
        int p = ein[j];
        int local = p >> 20;
        int pos = base[local] + atomicAdd(&hist[local], 1);
        eout[pos] = p & 0xFFFFF;
    }
    __syncthreads();
    for (int j = t; j < cnt; j += 256) bucketed[s + j] = eout[j];  // coalesced
}

// ---- layer-0 aggregation (d=3): one thread/node, x is 1.2MB -> L2-resident ----
__global__ void agg3(const float* __restrict__ x, const int* __restrict__ rowstart,
                     const int* __restrict__ rowend, const int* __restrict__ csr,
                     float* __restrict__ out, int N) {
    int n = blockIdx.x * blockDim.x + threadIdx.x;
    if (n >= N) return;
    float a0 = x[n * 3], a1 = x[n * 3 + 1], a2 = x[n * 3 + 2];
    int s = rowstart[n], e = rowend[n];
    for (int j = s; j < e; j++) {
        int nb = csr[j];
        a0 += x[nb * 3];
        a1 += x[nb * 3 + 1];
        a2 += x[nb * 3 + 2];
    }
    out[n * 3] = a0;
    out[n * 3 + 1] = a1;
    out[n * 3 + 2] = a2;
}

// ---- layers 1-2 aggregation: 16 lanes/node, float4/lane, pure gather ----
__global__ __launch_bounds__(256) void agg64(
    const float* __restrict__ x, const int* __restrict__ rowstart,
    const int* __restrict__ rowend, const int* __restrict__ csr,
    float* __restrict__ out, int N) {
    int g = threadIdx.x >> 4, l = threadIdx.x & 15;
    int n = blockIdx.x * 16 + g;
    if (n >= N) return;
    const float4* xr = (const float4*)x;
    float4 acc = xr[n * 16 + l];  // self term: h = x + agg
    int s = rowstart[n], e = rowend[n];
    for (int j = s; j < e; j++) {
        int nb = csr[j];
        float4 v = xr[nb * 16 + l];
        acc.x += v.x; acc.y += v.y; acc.z += v.z; acc.w += v.w;
    }
    ((float4*)out)[n * 16 + l] = acc;
}

// ---- MLP: hout = relu(hin@W1+b1)@W2+b2, + fused BN sum/sumsq ----
__global__ __launch_bounds__(256) void mlp64(
    const float* __restrict__ hin, float* __restrict__ hout,
    const float* __restrict__ W1, const float* __restrict__ b1,
    const float* __restrict__ W2, const float* __restrict__ b2,
    float* __restrict__ bnsum, float* __restrict__ bnsq,
    int kin, int N) {
    __shared__ __align__(16) float w1s[64 * 64];
    __shared__ __align__(16) float w2s[64 * 64];
    __shared__ float b1s[64], b2s[64];
    __shared__ float hp[16][68];  // +4 pad
    __shared__ float ts[16][68];
    int t = threadIdx.x;
    for (int i = t; i < kin * 64; i += 256) w1s[i] = W1[i];
    for (int i = t; i < 64 * 64; i += 256) w2s[i] = W2[i];
    if (t < 64) { b1s[t] = b1[t]; b2s[t] = b2[t]; }
    __syncthreads();
    int g = t >> 4, l = t & 15, f0 = l * 4;
    float s0 = 0.f, s1 = 0.f, s2 = 0.f, s3 = 0.f;
    float q0 = 0.f, q1 = 0.f, q2 = 0.f, q3 = 0.f;
    // grid=1250: 20000 nodes/sweep, 100000/20000 = 5 exact iters, no tail
    for (int n = blockIdx.x * 16 + g; n < N; n += gridDim.x * 16) {
        for (int k = l; k < kin; k += 16) hp[g][k] = hin[n * kin + k];
        __syncthreads();
        float a0 = b1s[f0], a1 = b1s[f0 + 1], a2 = b1s[f0 + 2], a3 = b1s[f0 + 3];
        for (int k = 0; k < kin; k++) {
            float h = hp[g][k];
            float4 w = *(const float4*)&w1s[k * 64 + f0];
            a0 += h * w.x; a1 += h * w.y; a2 += h * w.z; a3 += h * w.w;
        }
        ts[g][f0] = fmaxf(a0, 0.f);
        ts[g][f0 + 1] = fmaxf(a1, 0.f);
        ts[g][f0 + 2] = fmaxf(a2, 0.f);
        ts[g][f0 + 3] = fmaxf(a3, 0.f);
        __syncthreads();
        a0 = b2s[f0]; a1 = b2s[f0 + 1]; a2 = b2s[f0 + 2]; a3 = b2s[f0 + 3];
        for (int k = 0; k < 64; k++) {
            float h = ts[g][k];
            float4 w = *(const float4*)&w2s[k * 64 + f0];
            a0 += h * w.x; a1 += h * w.y; a2 += h * w.z; a3 += h * w.w;
        }
        float4 o; o.x = a0; o.y = a1; o.z = a2; o.w = a3;
        ((float4*)hout)[n * 16 + l] = o;
        s0 += a0; s1 += a1; s2 += a2; s3 += a3;
        q0 += a0 * a0; q1 += a1 * a1; q2 += a2 * a2; q3 += a3 * a3;
        __syncthreads();  // protect hp/ts reuse
    }
    __syncthreads();
    hp[g][f0] = s0; hp[g][f0 + 1] = s1; hp[g][f0 + 2] = s2; hp[g][f0 + 3] = s3;
    ts[g][f0] = q0; ts[g][f0 + 1] = q1; ts[g][f0 + 2] = q2; ts[g][f0 + 3] = q3;
    __syncthreads();
    if (t < 64) {
        float S = 0.f, Q = 0.f;
        for (int g2 = 0; g2 < 16; g2++) { S += hp[g2][t]; Q += ts[g2][t]; }
        atomicAdd(&bnsum[t], S);   // 1250 blocks x 64 addrs: low contention
        atomicAdd(&bnsq[t], Q);
    }
}

// ---- BN finalize + apply + ReLU (in place) ----
__global__ void bn_apply(float* __restrict__ h, const float* __restrict__ bnsum,
                         const float* __restrict__ bnsq, const float* __restrict__ gamma,
                         const float* __restrict__ beta, int N) {
    __shared__ float sc[64], sh[64];
    int t = threadIdx.x;
    if (t < 64) {
        float mu = bnsum[t] / (float)N;
        float var = bnsq[t] / (float)N - mu * mu;
        float s = gamma[t] * rsqrtf(var + 1e-5f);
        sc[t] = s;
        sh[t] = beta[t] - mu * s;
    }
    __syncthreads();
    int idx = blockIdx.x * 256 + t;
    if (idx >= N * 16) return;
    int f0 = (idx & 15) * 4;
    float4 v = ((float4*)h)[idx];
    v.x = fmaxf(v.x * sc[f0] + sh[f0], 0.f);
    v.y = fmaxf(v.y * sc[f0 + 1] + sh[f0 + 1], 0.f);
    v.z = fmaxf(v.z * sc[f0 + 2] + sh[f0 + 2], 0.f);
    v.w = fmaxf(v.w * sc[f0 + 3] + sh[f0 + 3], 0.f);
    ((float4*)h)[idx] = v;
}

// ---- last layer: BN finalize + apply + ReLU + pool atomics ----
__global__ void bn_apply_pool(const float* __restrict__ h, const int* __restrict__ batch,
                              const float* __restrict__ bnsum, const float* __restrict__ bnsq,
                              const float* __restrict__ gamma, const float* __restrict__ beta,
                              float* __restrict__ pool, float* __restrict__ cnt, int N) {
    __shared__ float sc[64], sh[64];
    int t = threadIdx.x;
    if (t < 64) {
        float mu = bnsum[t] / (float)N;
        float var = bnsq[t] / (float)N - mu * mu;
        float s = gamma[t] * rsqrtf(var + 1e-5f);
        sc[t] = s;
        sh[t] = beta[t] - mu * s;
    }
    __syncthreads();
    int idx = blockIdx.x * 256 + t;
    if (idx >= N * 16) return;
    int n = idx >> 4, l = idx & 15, f0 = l * 4;
    int bg = batch[n];
    float4 v = ((const float4*)h)[idx];
    v.x = fmaxf(v.x * sc[f0] + sh[f0], 0.f);
    v.y = fmaxf(v.y * sc[f0 + 1] + sh[f0 + 1], 0.f);
    v.z = fmaxf(v.z * sc[f0 + 2] + sh[f0 + 2], 0.f);
    v.w = fmaxf(v.w * sc[f0 + 3] + sh[f0 + 3], 0.f);
    float* pp = &pool[bg * 64 + f0];
    atomicAdd(pp + 0, v.x);
    atomicAdd(pp + 1, v.y);
    atomicAdd(pp + 2, v.z);
    atomicAdd(pp + 3, v.w);
    if (l == 0) atomicAdd(&cnt[bg], 1.0f);
}

__global__ void final_out(const float* __restrict__ pool, const float* __restrict__ cnt,
                          const float* __restrict__ wout, const float* __restrict__ bout,
                          float* __restrict__ out) {
    __shared__ float gr[64];
    int g = blockIdx.x, t = threadIdx.x;
    float c = cnt[g];
    float v = pool[g * 64 + t];
    gr[t] = (c > 0.f) ? v / fmaxf(c, 1.f) : 0.f;
    __syncthreads();
    float acc = bout[t];
    for (int f = 0; f < 64; f++) acc += gr[f] * wout[f * 64 + t];
    out[g * 64 + t] = acc;
}

extern "C" void kernel_launch(void* const* d_in, const int* in_sizes, int n_in,
                              void* d_out, int out_size, void* d_ws, size_t ws_size,
                              hipStream_t stream) {
    const float* x     = (const float*)d_in[0];
    const int*   ei    = (const int*)d_in[1];
    const int*   batch = (const int*)d_in[2];
    const float* w1_0  = (const float*)d_in[3];
    const float* w1_r  = (const float*)d_in[4];
    const float* b1    = (const float*)d_in[5];
    const float* w2    = (const float*)d_in[6];
    const float* b2    = (const float*)d_in[7];
    const float* gamma = (const float*)d_in[8];
    const float* beta  = (const float*)d_in[9];
    const float* wout  = (const float*)d_in[10];
    const float* bout  = (const float*)d_in[11];
    float* out = (float*)d_out;

    const int N = in_sizes[2];      // 100000
    const int E = in_sizes[1] / 2;  // 3200000
    const int G = out_size / HD;    // 512
    const int NB = (N + 127) >> 7;  // 782 buckets

    // Workspace layout (~68 MB)
    float* bufA = (float*)d_ws;                      // N*64
    float* bufB = bufA + (size_t)N * 64;             // N*64
    float* h3   = bufB + (size_t)N * 64;             // N*3
    int*   cursor  = (int*)(h3 + (size_t)N * 3);     // NBMAX  (zeroed region start)
    float* bnstats = (float*)(cursor + NBMAX);       // 6*64
    float* pool    = bnstats + 384;                  // G*64
    float* cnt     = pool + (size_t)G * 64;          // G      (zeroed region end)
    int*   rowstart = (int*)(cnt + G);               // N
    int*   rowend   = rowstart + N;                  // N
    int*   bucketed = rowend + N;                    // NB*CAP (~14.4 MB)

    const int* srcv = ei;
    const int* dstv = ei + E;

    size_t zero_bytes = (NBMAX + 384 + (size_t)G * 64 + G) * 4;
    hipMemsetAsync(cursor, 0, zero_bytes, stream);

    // --- CSR build: scatter into buckets, then per-bucket counting sort ---
    bucket_scatter<<<(E + CHUNK - 1) / CHUNK, 256, 0, stream>>>(srcv, dstv, cursor, bucketed, E);
    bucket_csr<<<NB, 256, 0, stream>>>(bucketed, cursor, rowstart, rowend, N);

    // --- Layer 0 (kin=3) ---
    agg3<<<(N + 255) / 256, 256, 0, stream>>>(x, rowstart, rowend, bucketed, h3, N);
    mlp64<<<1250, 256, 0, stream>>>(h3, bufA, w1_0, b1, w2, b2,
                                    bnstats, bnstats + 64, 3, N);
    bn_apply<<<(N * 16 + 255) / 256, 256, 0, stream>>>(bufA, bnstats, bnstats + 64,
                                                       gamma, beta, N);

    // --- Layer 1 ---
    agg64<<<(N + 15) / 16, 256, 0, stream>>>(bufA, rowstart, rowend, bucketed, bufB, N);
    mlp64<<<1250, 256, 0, stream>>>(bufB, bufA, w1_r, b1 + 64, w2 + 4096, b2 + 64,
                                    bnstats + 128, bnstats + 192, 64, N);
    bn_apply<<<(N * 16 + 255) / 256, 256, 0, stream>>>(bufA, bnstats + 128, bnstats + 192,
                                                       gamma + 64, beta + 64, N);

    // --- Layer 2 (BN apply fused with pool) ---
    agg64<<<(N + 15) / 16, 256, 0, stream>>>(bufA, rowstart, rowend, bucketed, bufB, N);
    mlp64<<<1250, 256, 0, stream>>>(bufB, bufA, w1_r + 4096, b1 + 128, w2 + 8192, b2 + 128,
                                    bnstats + 256, bnstats + 320, 64, N);
    bn_apply_pool<<<(N * 16 + 255) / 256, 256, 0, stream>>>(bufA, batch,
                                                            bnstats + 256, bnstats + 320,
                                                            gamma + 128, beta + 128,
                                                            pool, cnt, N);

    final_out<<<G, 64, 0, stream>>>(pool, cnt, wout, bout, out);
}

// Round 4
// 639.046 us; speedup vs baseline: 5.1595x; 1.3435x over previous
//
#include <hip/hip_runtime.h>

// GIN encoder: N=100k nodes, E=3.2M edges, G=512 graphs, H=64, L=3.
// Round 4: kill all high-volume float atomics.
//  - Pooling: batch is SORTED -> one block per graph, binary-search node range,
//    coalesced column reduction, fused BN-apply + final matmul. No atomics.
//  - BN apply fused into the consumer (agg64_bn applies relu(h*sc+sh) per
//    gathered row; agg is latency-bound so extra VALU is free).
// CSR build: bucket scatter (dst>>7) + per-bucket LDS counting sort (round 3,
// verified fast). MLP keeps fused BN-stats epilogue. 10 launches.

#define HD 64
#define NBMAX 1024       // max buckets (N <= 131072)
#define CAP 4608         // bucket capacity; mean 4092, ~8 sigma margin
#define CHUNK 8192       // edges per scatter block

// ---- stage 1: bucketed[b*CAP + r] = src | (dstLocal<<20), contiguous runs ----
__global__ __launch_bounds__(256) void bucket_scatter(
    const int* __restrict__ src, const int* __restrict__ dst,
    int* __restrict__ cursor, int* __restrict__ bucketed, int E) {
    __shared__ int h[NBMAX];
    __shared__ int base[NBMAX];
    int t = threadIdx.x;
    for (int i = t; i < NBMAX; i += 256) h[i] = 0;
    __syncthreads();
    int e0 = blockIdx.x * CHUNK, e1 = min(e0 + CHUNK, E);
    for (int e = e0 + t; e < e1; e += 256) atomicAdd(&h[dst[e] >> 7], 1);
    __syncthreads();
    for (int i = t; i < NBMAX; i += 256) {
        int v = h[i];
        base[i] = v ? atomicAdd(&cursor[i], v) : 0;
        h[i] = 0;  // reuse as intra-block rank counter
    }
    __syncthreads();
    for (int e = e0 + t; e < e1; e += 256) {
        int d = dst[e];
        int bk = d >> 7;
        int r = base[bk] + atomicAdd(&h[bk], 1);
        if (r < CAP) bucketed[bk * CAP + r] = src[e] | ((d & 127) << 20);
    }
}

// ---- stage 2: per-bucket counting sort -> CSR (in place), rowstart/rowend ----
__global__ __launch_bounds__(256) void bucket_csr(
    int* __restrict__ bucketed, const int* __restrict__ bcnt,
    int* __restrict__ rowstart, int* __restrict__ rowend, int N) {
    __shared__ int ein[CAP];
    __shared__ int eout[CAP];
    __shared__ int hist[128];
    __shared__ int base[129];
    int b = blockIdx.x, t = threadIdx.x;
    int s = b * CAP, node0 = b << 7;
    int cnt = min(bcnt[b], CAP);
    if (t < 128) hist[t] = 0;
    __syncthreads();
    for (int j = t; j < cnt; j += 256) {
        int p = bucketed[s + j];
        ein[j] = p;
        atomicAdd(&hist[p >> 20], 1);
    }
    __syncthreads();
    if (t < 128) base[t + 1] = hist[t];
    if (t == 0) base[0] = 0;
    __syncthreads();
    for (int off = 1; off < 128; off <<= 1) {
        int v = 0;
        if (t < 128 && (t + 1) > off) v = base[t + 1 - off];
        __syncthreads();
        if (t < 128 && (t + 1) > off) base[t + 1] += v;
        __syncthreads();
    }
    if (t < 128) {
        int n = node0 + t;
        if (n < N) {
            rowstart[n] = s + base[t];
            rowend[n] = s + base[t + 1];
        }
        hist[t] = 0;  // reuse as per-row cursor
    }
    __syncthreads();
    for (int j = t; j < cnt; j += 256) {
        int p = ein[j];
        int local = p >> 20;
        int pos = base[local] + atomicAdd(&hist[local], 1);
        eout[pos] = p & 0xFFFFF;
    }
    __syncthreads();
    for (int j = t; j < cnt; j += 256) bucketed[s + j] = eout[j];  // coalesced
}

// ---- layer-0 aggregation (d=3): one thread/node, x is 1.2MB cache-resident ----
__global__ void agg3(const float* __restrict__ x, const int* __restrict__ rowstart,
                     const int* __restrict__ rowend, const int* __restrict__ csr,
                     float* __restrict__ out, int N) {
    int n = blockIdx.x * blockDim.x + threadIdx.x;
    if (n >= N) return;
    float a0 = x[n * 3], a1 = x[n * 3 + 1], a2 = x[n * 3 + 2];
    int s = rowstart[n], e = rowend[n];
    for (int j = s; j < e; j++) {
        int nb = csr[j];
        a0 += x[nb * 3];
        a1 += x[nb * 3 + 1];
        a2 += x[nb * 3 + 2];
    }
    out[n * 3] = a0;
    out[n * 3 + 1] = a1;
    out[n * 3 + 2] = a2;
}

// ---- layers 1-2 aggregation + fused BN apply: x_eff = relu(h*sc+sh) ----
// 16 lanes/node, float4/lane; agg is latency-bound so per-gather BN is free.
__global__ __launch_bounds__(256) void agg64_bn(
    const float* __restrict__ h, const int* __restrict__ rowstart,
    const int* __restrict__ rowend, const int* __restrict__ csr,
    const float* __restrict__ bnsum, const float* __restrict__ bnsq,
    const float* __restrict__ gamma, const float* __restrict__ beta,
    float* __restrict__ out, int N) {
    __shared__ float scs[64], shs[64];
    int t = threadIdx.x;
    if (t < 64) {
        float mu = bnsum[t] / (float)N;
        float var = bnsq[t] / (float)N - mu * mu;
        float s = gamma[t] * rsqrtf(var + 1e-5f);
        scs[t] = s;
        shs[t] = beta[t] - mu * s;
    }
    __syncthreads();
    int g = t >> 4, l = t & 15;
    int n = blockIdx.x * 16 + g;
    if (n >= N) return;
    int f0 = l * 4;
    float4 sc = *(const float4*)&scs[f0];
    float4 sh = *(const float4*)&shs[f0];
    const float4* xr = (const float4*)h;
    float4 v = xr[n * 16 + l];  // self term
    float4 acc;
    acc.x = fmaxf(v.x * sc.x + sh.x, 0.f);
    acc.y = fmaxf(v.y * sc.y + sh.y, 0.f);
    acc.z = fmaxf(v.z * sc.z + sh.z, 0.f);
    acc.w = fmaxf(v.w * sc.w + sh.w, 0.f);
    int s = rowstart[n], e = rowend[n];
    for (int j = s; j < e; j++) {
        int nb = csr[j];
        float4 w = xr[nb * 16 + l];
        acc.x += fmaxf(w.x * sc.x + sh.x, 0.f);
        acc.y += fmaxf(w.y * sc.y + sh.y, 0.f);
        acc.z += fmaxf(w.z * sc.z + sh.z, 0.f);
        acc.w += fmaxf(w.w * sc.w + sh.w, 0.f);
    }
    ((float4*)out)[n * 16 + l] = acc;
}

// ---- MLP: hout = relu(hin@W1+b1)@W2+b2, + fused BN sum/sumsq ----
__global__ __launch_bounds__(256) void mlp64(
    const float* __restrict__ hin, float* __restrict__ hout,
    const float* __restrict__ W1, const float* __restrict__ b1,
    const float* __restrict__ W2, const float* __restrict__ b2,
    float* __restrict__ bnsum, float* __restrict__ bnsq,
    int kin, int N) {
    __shared__ __align__(16) float w1s[64 * 64];
    __shared__ __align__(16) float w2s[64 * 64];
    __shared__ float b1s[64], b2s[64];
    __shared__ float hp[16][68];  // +4 pad
    __shared__ float ts[16][68];
    int t = threadIdx.x;
    for (int i = t; i < kin * 64; i += 256) w1s[i] = W1[i];
    for (int i = t; i < 64 * 64; i += 256) w2s[i] = W2[i];
    if (t < 64) { b1s[t] = b1[t]; b2s[t] = b2[t]; }
    __syncthreads();
    int g = t >> 4, l = t & 15, f0 = l * 4;
    float s0 = 0.f, s1 = 0.f, s2 = 0.f, s3 = 0.f;
    float q0 = 0.f, q1 = 0.f, q2 = 0.f, q3 = 0.f;
    // grid=1250: 20000 nodes/sweep, 100000/20000 = 5 exact iters, no tail
    for (int n = blockIdx.x * 16 + g; n < N; n += gridDim.x * 16) {
        for (int k = l; k < kin; k += 16) hp[g][k] = hin[n * kin + k];
        __syncthreads();
        float a0 = b1s[f0], a1 = b1s[f0 + 1], a2 = b1s[f0 + 2], a3 = b1s[f0 + 3];
        for (int k = 0; k < kin; k++) {
            float h = hp[g][k];
            float4 w = *(const float4*)&w1s[k * 64 + f0];
            a0 += h * w.x; a1 += h * w.y; a2 += h * w.z; a3 += h * w.w;
        }
        ts[g][f0] = fmaxf(a0, 0.f);
        ts[g][f0 + 1] = fmaxf(a1, 0.f);
        ts[g][f0 + 2] = fmaxf(a2, 0.f);
        ts[g][f0 + 3] = fmaxf(a3, 0.f);
        __syncthreads();
        a0 = b2s[f0]; a1 = b2s[f0 + 1]; a2 = b2s[f0 + 2]; a3 = b2s[f0 + 3];
        for (int k = 0; k < 64; k++) {
            float h = ts[g][k];
            float4 w = *(const float4*)&w2s[k * 64 + f0];
            a0 += h * w.x; a1 += h * w.y; a2 += h * w.z; a3 += h * w.w;
        }
        float4 o; o.x = a0; o.y = a1; o.z = a2; o.w = a3;
        ((float4*)hout)[n * 16 + l] = o;
        s0 += a0; s1 += a1; s2 += a2; s3 += a3;
        q0 += a0 * a0; q1 += a1 * a1; q2 += a2 * a2; q3 += a3 * a3;
        __syncthreads();  // protect hp/ts reuse
    }
    __syncthreads();
    hp[g][f0] = s0; hp[g][f0 + 1] = s1; hp[g][f0 + 2] = s2; hp[g][f0 + 3] = s3;
    ts[g][f0] = q0; ts[g][f0 + 1] = q1; ts[g][f0 + 2] = q2; ts[g][f0 + 3] = q3;
    __syncthreads();
    if (t < 64) {
        float S = 0.f, Q = 0.f;
        for (int g2 = 0; g2 < 16; g2++) { S += hp[g2][t]; Q += ts[g2][t]; }
        atomicAdd(&bnsum[t], S);   // 1250 blocks x 64 addrs: low contention
        atomicAdd(&bnsq[t], Q);
    }
}

// ---- BN apply + mean-pool + output matmul, one block per graph (batch SORTED,
// so each graph's nodes are contiguous; zero atomics) ----
__device__ __forceinline__ int lowb(const int* __restrict__ a, int n, int v) {
    int lo = 0, hi = n;
    while (lo < hi) {
        int m = (lo + hi) >> 1;
        if (a[m] < v) lo = m + 1; else hi = m;
    }
    return lo;
}

__global__ __launch_bounds__(256) void bn_pool_out(
    const float* __restrict__ h, const int* __restrict__ batch,
    const float* __restrict__ bnsum, const float* __restrict__ bnsq,
    const float* __restrict__ gamma, const float* __restrict__ beta,
    const float* __restrict__ wout, const float* __restrict__ bout,
    float* __restrict__ out, int N) {
    __shared__ float sc[64], sh[64];
    __shared__ float part[4][64];
    __shared__ float gr[64];
    __shared__ int range[2];
    int g = blockIdx.x, t = threadIdx.x;
    if (t < 64) {
        float mu = bnsum[t] / (float)N;
        float var = bnsq[t] / (float)N - mu * mu;
        float s = gamma[t] * rsqrtf(var + 1e-5f);
        sc[t] = s;
        sh[t] = beta[t] - mu * s;
    }
    if (t == 64) range[0] = lowb(batch, N, g);
    if (t == 65) range[1] = lowb(batch, N, g + 1);
    __syncthreads();
    int s0 = range[0], s1 = range[1];
    int col = t & 63, ro = t >> 6;
    float acc = 0.f;
    for (int n = s0 + ro; n < s1; n += 4) {
        float v = h[n * 64 + col];
        acc += fmaxf(v * sc[col] + sh[col], 0.f);
    }
    part[ro][col] = acc;
    __syncthreads();
    if (t < 64) {
        float S = part[0][t] + part[1][t] + part[2][t] + part[3][t];
        float c = (float)(s1 - s0);
        gr[t] = (c > 0.f) ? S / c : 0.f;
    }
    __syncthreads();
    if (t < 64) {
        float a = bout[t];
        for (int f = 0; f < 64; f++) a += gr[f] * wout[f * 64 + t];
        out[g * 64 + t] = a;
    }
}

extern "C" void kernel_launch(void* const* d_in, const int* in_sizes, int n_in,
                              void* d_out, int out_size, void* d_ws, size_t ws_size,
                              hipStream_t stream) {
    const float* x     = (const float*)d_in[0];
    const int*   ei    = (const int*)d_in[1];
    const int*   batch = (const int*)d_in[2];
    const float* w1_0  = (const float*)d_in[3];
    const float* w1_r  = (const float*)d_in[4];
    const float* b1    = (const float*)d_in[5];
    const float* w2    = (const float*)d_in[6];
    const float* b2    = (const float*)d_in[7];
    const float* gamma = (const float*)d_in[8];
    const float* beta  = (const float*)d_in[9];
    const float* wout  = (const float*)d_in[10];
    const float* bout  = (const float*)d_in[11];
    float* out = (float*)d_out;

    const int N = in_sizes[2];      // 100000
    const int E = in_sizes[1] / 2;  // 3200000
    const int NB = (N + 127) >> 7;  // 782 buckets

    // Workspace layout (~67 MB)
    float* bufA = (float*)d_ws;                      // N*64
    float* bufB = bufA + (size_t)N * 64;             // N*64
    float* h3   = bufB + (size_t)N * 64;             // N*3
    int*   cursor  = (int*)(h3 + (size_t)N * 3);     // NBMAX  (zeroed region start)
    float* bnstats = (float*)(cursor + NBMAX);       // 6*64   (zeroed region end)
    int*   rowstart = (int*)(bnstats + 384);         // N
    int*   rowend   = rowstart + N;                  // N
    int*   bucketed = rowend + N;                    // NB*CAP (~14.4 MB)

    const int* srcv = ei;
    const int* dstv = ei + E;

    hipMemsetAsync(cursor, 0, (NBMAX + 384) * 4, stream);

    // --- CSR build ---
    bucket_scatter<<<(E + CHUNK - 1) / CHUNK, 256, 0, stream>>>(srcv, dstv, cursor, bucketed, E);
    bucket_csr<<<NB, 256, 0, stream>>>(bucketed, cursor, rowstart, rowend, N);

    // --- Layer 0 (kin=3) ---
    agg3<<<(N + 255) / 256, 256, 0, stream>>>(x, rowstart, rowend, bucketed, h3, N);
    mlp64<<<1250, 256, 0, stream>>>(h3, bufA, w1_0, b1, w2, b2,
                                    bnstats, bnstats + 64, 3, N);

    // --- Layer 1 (agg fuses BN0 apply) ---
    agg64_bn<<<(N + 15) / 16, 256, 0, stream>>>(bufA, rowstart, rowend, bucketed,
                                                bnstats, bnstats + 64, gamma, beta,
                                                bufB, N);
    mlp64<<<1250, 256, 0, stream>>>(bufB, bufA, w1_r, b1 + 64, w2 + 4096, b2 + 64,
                                    bnstats + 128, bnstats + 192, 64, N);

    // --- Layer 2 (agg fuses BN1 apply) ---
    agg64_bn<<<(N + 15) / 16, 256, 0, stream>>>(bufA, rowstart, rowend, bucketed,
                                                bnstats + 128, bnstats + 192,
                                                gamma + 64, beta + 64, bufB, N);
    mlp64<<<1250, 256, 0, stream>>>(bufB, bufA, w1_r + 4096, b1 + 128, w2 + 8192, b2 + 128,
                                    bnstats + 256, bnstats + 320, 64, N);

    // --- BN2 apply + pool + output matmul (batch sorted -> no atomics) ---
    bn_pool_out<<<512, 256, 0, stream>>>(bufA, batch, bnstats + 256, bnstats + 320,
                                         gamma + 128, beta + 128, wout, bout, out, N);
}

// Round 5
// 579.008 us; speedup vs baseline: 5.6944x; 1.1037x over previous
//
#include <hip/hip_runtime.h>

// GIN encoder: N=100k nodes, E=3.2M edges, G=512 graphs, H=64, L=3.
// Round 5:
//  - agg64_bn/agg3: neighbor loop unrolled x4 with 4 independent accumulators
//    (round-4 counters: VMEM issue 2%, VALU 20% -> latency-bound, <1
//    outstanding gather; 4 outstanding ~ 4x MLP).
//  - MLP rewritten as register-tiled GEMM: 64-node tiles, k-major LDS (one
//    xT buffer reused for input then mid activations), thread owns 4 nodes x
//    4 cols -> per k: 2 broadcast ds_read_b128 vs 16 v_fma -> FMA-bound.
// CSR build (bucket scatter + per-bucket counting sort) and bn_pool_out kept.

#define HD 64
#define NBMAX 1024       // max buckets (N <= 131072)
#define CAP 4608         // bucket capacity; mean 4092, ~8 sigma margin
#define CHUNK 8192       // edges per scatter block
#define XT_STRIDE 68     // k-major LDS row stride (16B aligned, conflict-light)

// ---- stage 1: bucketed[b*CAP + r] = src | (dstLocal<<20), contiguous runs ----
__global__ __launch_bounds__(256) void bucket_scatter(
    const int* __restrict__ src, const int* __restrict__ dst,
    int* __restrict__ cursor, int* __restrict__ bucketed, int E) {
    __shared__ int h[NBMAX];
    __shared__ int base[NBMAX];
    int t = threadIdx.x;
    for (int i = t; i < NBMAX; i += 256) h[i] = 0;
    __syncthreads();
    int e0 = blockIdx.x * CHUNK, e1 = min(e0 + CHUNK, E);
    for (int e = e0 + t; e < e1; e += 256) atomicAdd(&h[dst[e] >> 7], 1);
    __syncthreads();
    for (int i = t; i < NBMAX; i += 256) {
        int v = h[i];
        base[i] = v ? atomicAdd(&cursor[i], v) : 0;
        h[i] = 0;  // reuse as intra-block rank counter
    }
    __syncthreads();
    for (int e = e0 + t; e < e1; e += 256) {
        int d = dst[e];
        int bk = d >> 7;
        int r = base[bk] + atomicAdd(&h[bk], 1);
        if (r < CAP) bucketed[bk * CAP + r] = src[e] | ((d & 127) << 20);
    }
}

// ---- stage 2: per-bucket counting sort -> CSR (in place), rowstart/rowend ----
__global__ __launch_bounds__(256) void bucket_csr(
    int* __restrict__ bucketed, const int* __restrict__ bcnt,
    int* __restrict__ rowstart, int* __restrict__ rowend, int N) {
    __shared__ int ein[CAP];
    __shared__ int eout[CAP];
    __shared__ int hist[128];
    __shared__ int base[129];
    int b = blockIdx.x, t = threadIdx.x;
    int s = b * CAP, node0 = b << 7;
    int cnt = min(bcnt[b], CAP);
    if (t < 128) hist[t] = 0;
    __syncthreads();
    for (int j = t; j < cnt; j += 256) {
        int p = bucketed[s + j];
        ein[j] = p;
        atomicAdd(&hist[p >> 20], 1);
    }
    __syncthreads();
    if (t < 128) base[t + 1] = hist[t];
    if (t == 0) base[0] = 0;
    __syncthreads();
    for (int off = 1; off < 128; off <<= 1) {
        int v = 0;
        if (t < 128 && (t + 1) > off) v = base[t + 1 - off];
        __syncthreads();
        if (t < 128 && (t + 1) > off) base[t + 1] += v;
        __syncthreads();
    }
    if (t < 128) {
        int n = node0 + t;
        if (n < N) {
            rowstart[n] = s + base[t];
            rowend[n] = s + base[t + 1];
        }
        hist[t] = 0;  // reuse as per-row cursor
    }
    __syncthreads();
    for (int j = t; j < cnt; j += 256) {
        int p = ein[j];
        int local = p >> 20;
        int pos = base[local] + atomicAdd(&hist[local], 1);
        eout[pos] = p & 0xFFFFF;
    }
    __syncthreads();
    for (int j = t; j < cnt; j += 256) bucketed[s + j] = eout[j];  // coalesced
}

// ---- layer-0 aggregation (d=3): one thread/node, unrolled x4 ----
__global__ void agg3(const float* __restrict__ x, const int* __restrict__ rowstart,
                     const int* __restrict__ rowend, const int* __restrict__ csr,
                     float* __restrict__ out, int N) {
    int n = blockIdx.x * blockDim.x + threadIdx.x;
    if (n >= N) return;
    float a0 = x[n * 3], a1 = x[n * 3 + 1], a2 = x[n * 3 + 2];
    float b0 = 0.f, b1 = 0.f, b2 = 0.f;
    float c0 = 0.f, c1 = 0.f, c2 = 0.f;
    float d0 = 0.f, d1 = 0.f, d2 = 0.f;
    int s = rowstart[n], e = rowend[n];
    int j = s;
    for (; j + 3 < e; j += 4) {
        int i0 = csr[j], i1 = csr[j + 1], i2 = csr[j + 2], i3 = csr[j + 3];
        a0 += x[i0 * 3]; a1 += x[i0 * 3 + 1]; a2 += x[i0 * 3 + 2];
        b0 += x[i1 * 3]; b1 += x[i1 * 3 + 1]; b2 += x[i1 * 3 + 2];
        c0 += x[i2 * 3]; c1 += x[i2 * 3 + 1]; c2 += x[i2 * 3 + 2];
        d0 += x[i3 * 3]; d1 += x[i3 * 3 + 1]; d2 += x[i3 * 3 + 2];
    }
    for (; j < e; j++) {
        int nb = csr[j];
        a0 += x[nb * 3]; a1 += x[nb * 3 + 1]; a2 += x[nb * 3 + 2];
    }
    out[n * 3] = a0 + b0 + c0 + d0;
    out[n * 3 + 1] = a1 + b1 + c1 + d1;
    out[n * 3 + 2] = a2 + b2 + c2 + d2;
}

// ---- layers 1-2 aggregation + fused BN apply, unrolled x4 (4 outstanding
// gathers per wave; BN+ReLU applied per gathered row before summing) ----
__global__ __launch_bounds__(256) void agg64_bn(
    const float* __restrict__ h, const int* __restrict__ rowstart,
    const int* __restrict__ rowend, const int* __restrict__ csr,
    const float* __restrict__ bnsum, const float* __restrict__ bnsq,
    const float* __restrict__ gamma, const float* __restrict__ beta,
    float* __restrict__ out, int N) {
    __shared__ float scs[64], shs[64];
    int t = threadIdx.x;
    if (t < 64) {
        float mu = bnsum[t] / (float)N;
        float var = bnsq[t] / (float)N - mu * mu;
        float s = gamma[t] * rsqrtf(var + 1e-5f);
        scs[t] = s;
        shs[t] = beta[t] - mu * s;
    }
    __syncthreads();
    int g = t >> 4, l = t & 15;
    int n = blockIdx.x * 16 + g;
    if (n >= N) return;
    int f0 = l * 4;
    float4 sc = *(const float4*)&scs[f0];
    float4 sh = *(const float4*)&shs[f0];
    const float4* xr = (const float4*)h;
    float4 v = xr[n * 16 + l];  // self term
    float4 A, B, C, D;
    A.x = fmaxf(v.x * sc.x + sh.x, 0.f);
    A.y = fmaxf(v.y * sc.y + sh.y, 0.f);
    A.z = fmaxf(v.z * sc.z + sh.z, 0.f);
    A.w = fmaxf(v.w * sc.w + sh.w, 0.f);
    B = make_float4(0.f, 0.f, 0.f, 0.f);
    C = B; D = B;
    int s = rowstart[n], e = rowend[n];
    int j = s;
    for (; j + 3 < e; j += 4) {
        int i0 = csr[j], i1 = csr[j + 1], i2 = csr[j + 2], i3 = csr[j + 3];
        float4 w0 = xr[i0 * 16 + l];
        float4 w1 = xr[i1 * 16 + l];
        float4 w2 = xr[i2 * 16 + l];
        float4 w3 = xr[i3 * 16 + l];
        A.x += fmaxf(w0.x * sc.x + sh.x, 0.f);
        A.y += fmaxf(w0.y * sc.y + sh.y, 0.f);
        A.z += fmaxf(w0.z * sc.z + sh.z, 0.f);
        A.w += fmaxf(w0.w * sc.w + sh.w, 0.f);
        B.x += fmaxf(w1.x * sc.x + sh.x, 0.f);
        B.y += fmaxf(w1.y * sc.y + sh.y, 0.f);
        B.z += fmaxf(w1.z * sc.z + sh.z, 0.f);
        B.w += fmaxf(w1.w * sc.w + sh.w, 0.f);
        C.x += fmaxf(w2.x * sc.x + sh.x, 0.f);
        C.y += fmaxf(w2.y * sc.y + sh.y, 0.f);
        C.z += fmaxf(w2.z * sc.z + sh.z, 0.f);
        C.w += fmaxf(w2.w * sc.w + sh.w, 0.f);
        D.x += fmaxf(w3.x * sc.x + sh.x, 0.f);
        D.y += fmaxf(w3.y * sc.y + sh.y, 0.f);
        D.z += fmaxf(w3.z * sc.z + sh.z, 0.f);
        D.w += fmaxf(w3.w * sc.w + sh.w, 0.f);
    }
    for (; j < e; j++) {
        int nb = csr[j];
        float4 w = xr[nb * 16 + l];
        A.x += fmaxf(w.x * sc.x + sh.x, 0.f);
        A.y += fmaxf(w.y * sc.y + sh.y, 0.f);
        A.z += fmaxf(w.z * sc.z + sh.z, 0.f);
        A.w += fmaxf(w.w * sc.w + sh.w, 0.f);
    }
    float4 acc;
    acc.x = (A.x + B.x) + (C.x + D.x);
    acc.y = (A.y + B.y) + (C.y + D.y);
    acc.z = (A.z + B.z) + (C.z + D.z);
    acc.w = (A.w + B.w) + (C.w + D.w);
    ((float4*)out)[n * 16 + l] = acc;
}

// ---- MLP as register-tiled GEMM: 64-node tile/block-iter. Thread (nq,f4)
// owns nodes nq*4..+3 x cols f4*4..+3. k-major LDS xT reused for hp then ts.
// Per k: 2 broadcast ds_read_b128 + 16 v_fma -> FMA-bound. Fused BN stats. ----
template <int KIN>
__global__ __launch_bounds__(256) void mlp_gemm(
    const float* __restrict__ hin, float* __restrict__ hout,
    const float* __restrict__ W1, const float* __restrict__ b1,
    const float* __restrict__ W2, const float* __restrict__ b2,
    float* __restrict__ bnsum, float* __restrict__ bnsq, int N) {
    __shared__ __align__(16) float w1s[KIN * 64];
    __shared__ __align__(16) float w2s[64 * 64];
    __shared__ __align__(16) float xT[64][XT_STRIDE];  // k-major; hp then ts
    __shared__ float b1s[64], b2s[64];
    int t = threadIdx.x;
    for (int i = t; i < KIN * 64; i += 256) w1s[i] = W1[i];
    for (int i = t; i < 64 * 64; i += 256) w2s[i] = W2[i];
    if (t < 64) { b1s[t] = b1[t]; b2s[t] = b2[t]; }
    int f4 = t & 15, f0 = f4 * 4;
    int nq = t >> 4;
    float bs0 = 0.f, bs1 = 0.f, bs2 = 0.f, bs3 = 0.f;
    float bq0 = 0.f, bq1 = 0.f, bq2 = 0.f, bq3 = 0.f;
    for (int base = blockIdx.x * 64; base < N; base += gridDim.x * 64) {
        __syncthreads();  // xT safe to overwrite (also covers weight staging)
        for (int idx = t; idx < 64 * KIN; idx += 256) {
            int n = idx / KIN, k = idx - n * KIN;
            int gn = base + n;
            xT[k][n] = (gn < N) ? hin[(size_t)gn * KIN + k] : 0.f;
        }
        __syncthreads();
        // GEMM1: node nq*4+j, cols f0..f0+3
        float4 c0, c1, c2, c3;
        c0 = *(const float4*)&b1s[f0];
        c1 = c0; c2 = c0; c3 = c0;
        for (int k = 0; k < KIN; k++) {
            float4 w = *(const float4*)&w1s[k * 64 + f0];
            float4 hv = *(const float4*)&xT[k][nq * 4];
            c0.x += hv.x * w.x; c0.y += hv.x * w.y; c0.z += hv.x * w.z; c0.w += hv.x * w.w;
            c1.x += hv.y * w.x; c1.y += hv.y * w.y; c1.z += hv.y * w.z; c1.w += hv.y * w.w;
            c2.x += hv.z * w.x; c2.y += hv.z * w.y; c2.z += hv.z * w.z; c2.w += hv.z * w.w;
            c3.x += hv.w * w.x; c3.y += hv.w * w.y; c3.z += hv.w * w.z; c3.w += hv.w * w.w;
        }
        __syncthreads();  // all reads of xT (hp) done
        int n0 = nq * 4;
        xT[f0 + 0][n0 + 0] = fmaxf(c0.x, 0.f);
        xT[f0 + 1][n0 + 0] = fmaxf(c0.y, 0.f);
        xT[f0 + 2][n0 + 0] = fmaxf(c0.z, 0.f);
        xT[f0 + 3][n0 + 0] = fmaxf(c0.w, 0.f);
        xT[f0 + 0][n0 + 1] = fmaxf(c1.x, 0.f);
        xT[f0 + 1][n0 + 1] = fmaxf(c1.y, 0.f);
        xT[f0 + 2][n0 + 1] = fmaxf(c1.z, 0.f);
        xT[f0 + 3][n0 + 1] = fmaxf(c1.w, 0.f);
        xT[f0 + 0][n0 + 2] = fmaxf(c2.x, 0.f);
        xT[f0 + 1][n0 + 2] = fmaxf(c2.y, 0.f);
        xT[f0 + 2][n0 + 2] = fmaxf(c2.z, 0.f);
        xT[f0 + 3][n0 + 2] = fmaxf(c2.w, 0.f);
        xT[f0 + 0][n0 + 3] = fmaxf(c3.x, 0.f);
        xT[f0 + 1][n0 + 3] = fmaxf(c3.y, 0.f);
        xT[f0 + 2][n0 + 3] = fmaxf(c3.z, 0.f);
        xT[f0 + 3][n0 + 3] = fmaxf(c3.w, 0.f);
        __syncthreads();
        // GEMM2
        float4 d0, d1, d2, d3;
        d0 = *(const float4*)&b2s[f0];
        d1 = d0; d2 = d0; d3 = d0;
        for (int k = 0; k < 64; k++) {
            float4 w = *(const float4*)&w2s[k * 64 + f0];
            float4 hv = *(const float4*)&xT[k][nq * 4];
            d0.x += hv.x * w.x; d0.y += hv.x * w.y; d0.z += hv.x * w.z; d0.w += hv.x * w.w;
            d1.x += hv.y * w.x; d1.y += hv.y * w.y; d1.z += hv.y * w.z; d1.w += hv.y * w.w;
            d2.x += hv.z * w.x; d2.y += hv.z * w.y; d2.z += hv.z * w.z; d2.w += hv.z * w.w;
            d3.x += hv.w * w.x; d3.y += hv.w * w.y; d3.z += hv.w * w.z; d3.w += hv.w * w.w;
        }
        int gn0 = base + n0;
        if (gn0 + 0 < N) {
            *(float4*)&hout[(size_t)(gn0 + 0) * 64 + f0] = d0;
            bs0 += d0.x; bs1 += d0.y; bs2 += d0.z; bs3 += d0.w;
            bq0 += d0.x * d0.x; bq1 += d0.y * d0.y; bq2 += d0.z * d0.z; bq3 += d0.w * d0.w;
        }
        if (gn0 + 1 < N) {
            *(float4*)&hout[(size_t)(gn0 + 1) * 64 + f0] = d1;
            bs0 += d1.x; bs1 += d1.y; bs2 += d1.z; bs3 += d1.w;
            bq0 += d1.x * d1.x; bq1 += d1.y * d1.y; bq2 += d1.z * d1.z; bq3 += d1.w * d1.w;
        }
        if (gn0 + 2 < N) {
            *(float4*)&hout[(size_t)(gn0 + 2) * 64 + f0] = d2;
            bs0 += d2.x; bs1 += d2.y; bs2 += d2.z; bs3 += d2.w;
            bq0 += d2.x * d2.x; bq1 += d2.y * d2.y; bq2 += d2.z * d2.z; bq3 += d2.w * d2.w;
        }
        if (gn0 + 3 < N) {
            *(float4*)&hout[(size_t)(gn0 + 3) * 64 + f0] = d3;
            bs0 += d3.x; bs1 += d3.y; bs2 += d3.z; bs3 += d3.w;
            bq0 += d3.x * d3.x; bq1 += d3.y * d3.y; bq2 += d3.z * d3.z; bq3 += d3.w * d3.w;
        }
    }
    // BN partial reduce across nq groups via xT
    __syncthreads();
    xT[nq][f0] = bs0; xT[nq][f0 + 1] = bs1; xT[nq][f0 + 2] = bs2; xT[nq][f0 + 3] = bs3;
    __syncthreads();
    if (t < 64) {
        float S = 0.f;
        for (int q = 0; q < 16; q++) S += xT[q][t];
        atomicAdd(&bnsum[t], S);
    }
    __syncthreads();
    xT[nq][f0] = bq0; xT[nq][f0 + 1] = bq1; xT[nq][f0 + 2] = bq2; xT[nq][f0 + 3] = bq3;
    __syncthreads();
    if (t < 64) {
        float Q = 0.f;
        for (int q = 0; q < 16; q++) Q += xT[q][t];
        atomicAdd(&bnsq[t], Q);
    }
}

// ---- BN apply + mean-pool + output matmul, one block per graph (batch
// sorted -> contiguous node ranges; zero atomics) ----
__device__ __forceinline__ int lowb(const int* __restrict__ a, int n, int v) {
    int lo = 0, hi = n;
    while (lo < hi) {
        int m = (lo + hi) >> 1;
        if (a[m] < v) lo = m + 1; else hi = m;
    }
    return lo;
}

__global__ __launch_bounds__(256) void bn_pool_out(
    const float* __restrict__ h, const int* __restrict__ batch,
    const float* __restrict__ bnsum, const float* __restrict__ bnsq,
    const float* __restrict__ gamma, const float* __restrict__ beta,
    const float* __restrict__ wout, const float* __restrict__ bout,
    float* __restrict__ out, int N) {
    __shared__ float sc[64], sh[64];
    __shared__ float part[4][64];
    __shared__ float gr[64];
    __shared__ int range[2];
    int g = blockIdx.x, t = threadIdx.x;
    if (t < 64) {
        float mu = bnsum[t] / (float)N;
        float var = bnsq[t] / (float)N - mu * mu;
        float s = gamma[t] * rsqrtf(var + 1e-5f);
        sc[t] = s;
        sh[t] = beta[t] - mu * s;
    }
    if (t == 64) range[0] = lowb(batch, N, g);
    if (t == 65) range[1] = lowb(batch, N, g + 1);
    __syncthreads();
    int s0 = range[0], s1 = range[1];
    int col = t & 63, ro = t >> 6;
    float acc = 0.f;
    for (int n = s0 + ro; n < s1; n += 4) {
        float v = h[n * 64 + col];
        acc += fmaxf(v * sc[col] + sh[col], 0.f);
    }
    part[ro][col] = acc;
    __syncthreads();
    if (t < 64) {
        float S = part[0][t] + part[1][t] + part[2][t] + part[3][t];
        float c = (float)(s1 - s0);
        gr[t] = (c > 0.f) ? S / c : 0.f;
    }
    __syncthreads();
    if (t < 64) {
        float a = bout[t];
        for (int f = 0; f < 64; f++) a += gr[f] * wout[f * 64 + t];
        out[g * 64 + t] = a;
    }
}

extern "C" void kernel_launch(void* const* d_in, const int* in_sizes, int n_in,
                              void* d_out, int out_size, void* d_ws, size_t ws_size,
                              hipStream_t stream) {
    const float* x     = (const float*)d_in[0];
    const int*   ei    = (const int*)d_in[1];
    const int*   batch = (const int*)d_in[2];
    const float* w1_0  = (const float*)d_in[3];
    const float* w1_r  = (const float*)d_in[4];
    const float* b1    = (const float*)d_in[5];
    const float* w2    = (const float*)d_in[6];
    const float* b2    = (const float*)d_in[7];
    const float* gamma = (const float*)d_in[8];
    const float* beta  = (const float*)d_in[9];
    const float* wout  = (const float*)d_in[10];
    const float* bout  = (const float*)d_in[11];
    float* out = (float*)d_out;

    const int N = in_sizes[2];      // 100000
    const int E = in_sizes[1] / 2;  // 3200000
    const int NB = (N + 127) >> 7;  // 782 buckets

    // Workspace layout (~67 MB)
    float* bufA = (float*)d_ws;                      // N*64
    float* bufB = bufA + (size_t)N * 64;             // N*64
    float* h3   = bufB + (size_t)N * 64;             // N*3
    int*   cursor  = (int*)(h3 + (size_t)N * 3);     // NBMAX  (zeroed region start)
    float* bnstats = (float*)(cursor + NBMAX);       // 6*64   (zeroed region end)
    int*   rowstart = (int*)(bnstats + 384);         // N
    int*   rowend   = rowstart + N;                  // N
    int*   bucketed = rowend + N;                    // NB*CAP (~14.4 MB)

    const int* srcv = ei;
    const int* dstv = ei + E;

    hipMemsetAsync(cursor, 0, (NBMAX + 384) * 4, stream);

    // --- CSR build ---
    bucket_scatter<<<(E + CHUNK - 1) / CHUNK, 256, 0, stream>>>(srcv, dstv, cursor, bucketed, E);
    bucket_csr<<<NB, 256, 0, stream>>>(bucketed, cursor, rowstart, rowend, N);

    // --- Layer 0 (kin=3) ---
    agg3<<<(N + 255) / 256, 256, 0, stream>>>(x, rowstart, rowend, bucketed, h3, N);
    mlp_gemm<3><<<782, 256, 0, stream>>>(h3, bufA, w1_0, b1, w2, b2,
                                         bnstats, bnstats + 64, N);

    // --- Layer 1 (agg fuses BN0 apply) ---
    agg64_bn<<<(N + 15) / 16, 256, 0, stream>>>(bufA, rowstart, rowend, bucketed,
                                                bnstats, bnstats + 64, gamma, beta,
                                                bufB, N);
    mlp_gemm<64><<<782, 256, 0, stream>>>(bufB, bufA, w1_r, b1 + 64, w2 + 4096, b2 + 64,
                                          bnstats + 128, bnstats + 192, N);

    // --- Layer 2 (agg fuses BN1 apply) ---
    agg64_bn<<<(N + 15) / 16, 256, 0, stream>>>(bufA, rowstart, rowend, bucketed,
                                                bnstats + 128, bnstats + 192,
                                                gamma + 64, beta + 64, bufB, N);
    mlp_gemm<64><<<782, 256, 0, stream>>>(bufB, bufA, w1_r + 4096, b1 + 128, w2 + 8192, b2 + 128,
                                          bnstats + 256, bnstats + 320, N);

    // --- BN2 apply + pool + output matmul (batch sorted -> no atomics) ---
    bn_pool_out<<<512, 256, 0, stream>>>(bufA, batch, bnstats + 256, bnstats + 320,
                                         gamma + 128, beta + 128, wout, bout, out, N);
}

// Round 6
// 476.398 us; speedup vs baseline: 6.9209x; 1.2154x over previous
//
#include <hip/hip_runtime.h>

// GIN encoder: N=100k nodes, E=3.2M edges, G=512 graphs, H=64, L=3.
// Round 6: bf16 gather path. agg64_bn at 3.6 TB/s TCC-miss BW was at the
// LLC-service ceiling -> halve bytes/edge. mlp_gemm writes bf16 (BN stats
// still fp32 in-kernel, so BN mu/sigma exact); agg gathers bf16 rows
// (128B/edge, 8 lanes x uint4/node), BN+ReLU in fp32 post-convert;
// bn_pool_out reads bf16. Agg output stays fp32 (sequential).

#define HD 64
#define NBMAX 1024       // max buckets (N <= 131072)
#define CAP 4608         // bucket capacity; mean 4092, ~8 sigma margin
#define CHUNK 8192       // edges per scatter block
#define XT_STRIDE 68     // k-major LDS row stride

// ---- stage 1: bucketed[b*CAP + r] = src | (dstLocal<<20), contiguous runs ----
__global__ __launch_bounds__(256) void bucket_scatter(
    const int* __restrict__ src, const int* __restrict__ dst,
    int* __restrict__ cursor, int* __restrict__ bucketed, int E) {
    __shared__ int h[NBMAX];
    __shared__ int base[NBMAX];
    int t = threadIdx.x;
    for (int i = t; i < NBMAX; i += 256) h[i] = 0;
    __syncthreads();
    int e0 = blockIdx.x * CHUNK, e1 = min(e0 + CHUNK, E);
    for (int e = e0 + t; e < e1; e += 256) atomicAdd(&h[dst[e] >> 7], 1);
    __syncthreads();
    for (int i = t; i < NBMAX; i += 256) {
        int v = h[i];
        base[i] = v ? atomicAdd(&cursor[i], v) : 0;
        h[i] = 0;  // reuse as intra-block rank counter
    }
    __syncthreads();
    for (int e = e0 + t; e < e1; e += 256) {
        int d = dst[e];
        int bk = d >> 7;
        int r = base[bk] + atomicAdd(&h[bk], 1);
        if (r < CAP) bucketed[bk * CAP + r] = src[e] | ((d & 127) << 20);
    }
}

// ---- stage 2: per-bucket counting sort -> CSR (in place), rowstart/rowend ----
__global__ __launch_bounds__(256) void bucket_csr(
    int* __restrict__ bucketed, const int* __restrict__ bcnt,
    int* __restrict__ rowstart, int* __restrict__ rowend, int N) {
    __shared__ int ein[CAP];
    __shared__ int eout[CAP];
    __shared__ int hist[128];
    __shared__ int base[129];
    int b = blockIdx.x, t = threadIdx.x;
    int s = b * CAP, node0 = b << 7;
    int cnt = min(bcnt[b], CAP);
    if (t < 128) hist[t] = 0;
    __syncthreads();
    for (int j = t; j < cnt; j += 256) {
        int p = bucketed[s + j];
        ein[j] = p;
        atomicAdd(&hist[p >> 20], 1);
    }
    __syncthreads();
    if (t < 128) base[t + 1] = hist[t];
    if (t == 0) base[0] = 0;
    __syncthreads();
    for (int off = 1; off < 128; off <<= 1) {
        int v = 0;
        if (t < 128 && (t + 1) > off) v = base[t + 1 - off];
        __syncthreads();
        if (t < 128 && (t + 1) > off) base[t + 1] += v;
        __syncthreads();
    }
    if (t < 128) {
        int n = node0 + t;
        if (n < N) {
            rowstart[n] = s + base[t];
            rowend[n] = s + base[t + 1];
        }
        hist[t] = 0;  // reuse as per-row cursor
    }
    __syncthreads();
    for (int j = t; j < cnt; j += 256) {
        int p = ein[j];
        int local = p >> 20;
        int pos = base[local] + atomicAdd(&hist[local], 1);
        eout[pos] = p & 0xFFFFF;
    }
    __syncthreads();
    for (int j = t; j < cnt; j += 256) bucketed[s + j] = eout[j];  // coalesced
}

// ---- layer-0 aggregation (d=3): one thread/node, unrolled x4 ----
__global__ void agg3(const float* __restrict__ x, const int* __restrict__ rowstart,
                     const int* __restrict__ rowend, const int* __restrict__ csr,
                     float* __restrict__ out, int N) {
    int n = blockIdx.x * blockDim.x + threadIdx.x;
    if (n >= N) return;
    float a0 = x[n * 3], a1 = x[n * 3 + 1], a2 = x[n * 3 + 2];
    float b0 = 0.f, b1 = 0.f, b2 = 0.f;
    float c0 = 0.f, c1 = 0.f, c2 = 0.f;
    float d0 = 0.f, d1 = 0.f, d2 = 0.f;
    int s = rowstart[n], e = rowend[n];
    int j = s;
    for (; j + 3 < e; j += 4) {
        int i0 = csr[j], i1 = csr[j + 1], i2 = csr[j + 2], i3 = csr[j + 3];
        a0 += x[i0 * 3]; a1 += x[i0 * 3 + 1]; a2 += x[i0 * 3 + 2];
        b0 += x[i1 * 3]; b1 += x[i1 * 3 + 1]; b2 += x[i1 * 3 + 2];
        c0 += x[i2 * 3]; c1 += x[i2 * 3 + 1]; c2 += x[i2 * 3 + 2];
        d0 += x[i3 * 3]; d1 += x[i3 * 3 + 1]; d2 += x[i3 * 3 + 2];
    }
    for (; j < e; j++) {
        int nb = csr[j];
        a0 += x[nb * 3]; a1 += x[nb * 3 + 1]; a2 += x[nb * 3 + 2];
    }
    out[n * 3] = a0 + b0 + c0 + d0;
    out[n * 3 + 1] = a1 + b1 + c1 + d1;
    out[n * 3 + 2] = a2 + b2 + c2 + d2;
}

// bf16x2 (packed in uint) -> accumulate relu(v*sc+sh) into a[8]
__device__ __forceinline__ void accum_bf16(const uint4 u,
                                           const float4 scA, const float4 scB,
                                           const float4 shA, const float4 shB,
                                           float* __restrict__ a) {
    a[0] += fmaxf(__uint_as_float(u.x << 16) * scA.x + shA.x, 0.f);
    a[1] += fmaxf(__uint_as_float(u.x & 0xFFFF0000u) * scA.y + shA.y, 0.f);
    a[2] += fmaxf(__uint_as_float(u.y << 16) * scA.z + shA.z, 0.f);
    a[3] += fmaxf(__uint_as_float(u.y & 0xFFFF0000u) * scA.w + shA.w, 0.f);
    a[4] += fmaxf(__uint_as_float(u.z << 16) * scB.x + shB.x, 0.f);
    a[5] += fmaxf(__uint_as_float(u.z & 0xFFFF0000u) * scB.y + shB.y, 0.f);
    a[6] += fmaxf(__uint_as_float(u.w << 16) * scB.z + shB.z, 0.f);
    a[7] += fmaxf(__uint_as_float(u.w & 0xFFFF0000u) * scB.w + shB.w, 0.f);
}

// ---- layers 1-2 aggregation + fused BN apply, bf16 rows (128B/edge).
// 8 lanes/node (uint4 = 8 bf16 each), 32 nodes/block, 4 gathers in flight. ----
__global__ __launch_bounds__(256) void agg64_bn(
    const unsigned short* __restrict__ h, const int* __restrict__ rowstart,
    const int* __restrict__ rowend, const int* __restrict__ csr,
    const float* __restrict__ bnsum, const float* __restrict__ bnsq,
    const float* __restrict__ gamma, const float* __restrict__ beta,
    float* __restrict__ out, int N) {
    __shared__ float scs[64], shs[64];
    int t = threadIdx.x;
    if (t < 64) {
        float mu = bnsum[t] / (float)N;
        float var = bnsq[t] / (float)N - mu * mu;
        float s = gamma[t] * rsqrtf(var + 1e-5f);
        scs[t] = s;
        shs[t] = beta[t] - mu * s;
    }
    __syncthreads();
    int g = t >> 3, l = t & 7;
    int n = blockIdx.x * 32 + g;
    if (n >= N) return;
    int c0 = l * 8;
    float4 scA = *(const float4*)&scs[c0], scB = *(const float4*)&scs[c0 + 4];
    float4 shA = *(const float4*)&shs[c0], shB = *(const float4*)&shs[c0 + 4];
    const uint4* hr = (const uint4*)h;  // one row = 8 uint4
    float A[8] = {0.f, 0.f, 0.f, 0.f, 0.f, 0.f, 0.f, 0.f};
    float B[8] = {0.f, 0.f, 0.f, 0.f, 0.f, 0.f, 0.f, 0.f};
    uint4 self = hr[(size_t)n * 8 + l];
    accum_bf16(self, scA, scB, shA, shB, A);
    int s = rowstart[n], e = rowend[n];
    int j = s;
    for (; j + 3 < e; j += 4) {
        int i0 = csr[j], i1 = csr[j + 1], i2 = csr[j + 2], i3 = csr[j + 3];
        uint4 w0 = hr[(size_t)i0 * 8 + l];
        uint4 w1 = hr[(size_t)i1 * 8 + l];
        uint4 w2 = hr[(size_t)i2 * 8 + l];
        uint4 w3 = hr[(size_t)i3 * 8 + l];
        accum_bf16(w0, scA, scB, shA, shB, A);
        accum_bf16(w1, scA, scB, shA, shB, B);
        accum_bf16(w2, scA, scB, shA, shB, A);
        accum_bf16(w3, scA, scB, shA, shB, B);
    }
    for (; j < e; j++) {
        uint4 w = hr[(size_t)csr[j] * 8 + l];
        accum_bf16(w, scA, scB, shA, shB, A);
    }
    float4 o0, o1;
    o0.x = A[0] + B[0]; o0.y = A[1] + B[1]; o0.z = A[2] + B[2]; o0.w = A[3] + B[3];
    o1.x = A[4] + B[4]; o1.y = A[5] + B[5]; o1.z = A[6] + B[6]; o1.w = A[7] + B[7];
    ((float4*)out)[(size_t)n * 16 + l * 2] = o0;
    ((float4*)out)[(size_t)n * 16 + l * 2 + 1] = o1;
}

// round-to-nearest-even bf16 pack of 2 floats into one uint
__device__ __forceinline__ unsigned bf16pack2(float a, float b) {
    unsigned ua = __float_as_uint(a);
    ua = (ua + 0x7FFFu + ((ua >> 16) & 1u)) >> 16;
    unsigned ub = __float_as_uint(b);
    ub = (ub + 0x7FFFu + ((ub >> 16) & 1u)) >> 16;
    return ua | (ub << 16);
}

// ---- MLP register-tiled GEMM; fp32 compute, bf16 output, fused BN stats ----
template <int KIN>
__global__ __launch_bounds__(256) void mlp_gemm(
    const float* __restrict__ hin, unsigned short* __restrict__ hout,
    const float* __restrict__ W1, const float* __restrict__ b1,
    const float* __restrict__ W2, const float* __restrict__ b2,
    float* __restrict__ bnsum, float* __restrict__ bnsq, int N) {
    __shared__ __align__(16) float w1s[KIN * 64];
    __shared__ __align__(16) float w2s[64 * 64];
    __shared__ __align__(16) float xT[64][XT_STRIDE];  // k-major; hp then ts
    __shared__ float b1s[64], b2s[64];
    int t = threadIdx.x;
    for (int i = t; i < KIN * 64; i += 256) w1s[i] = W1[i];
    for (int i = t; i < 64 * 64; i += 256) w2s[i] = W2[i];
    if (t < 64) { b1s[t] = b1[t]; b2s[t] = b2[t]; }
    int f4 = t & 15, f0 = f4 * 4;
    int nq = t >> 4;
    float bs0 = 0.f, bs1 = 0.f, bs2 = 0.f, bs3 = 0.f;
    float bq0 = 0.f, bq1 = 0.f, bq2 = 0.f, bq3 = 0.f;
    for (int base = blockIdx.x * 64; base < N; base += gridDim.x * 64) {
        __syncthreads();  // xT safe to overwrite (also covers weight staging)
        for (int idx = t; idx < 64 * KIN; idx += 256) {
            int n = idx / KIN, k = idx - n * KIN;
            int gn = base + n;
            xT[k][n] = (gn < N) ? hin[(size_t)gn * KIN + k] : 0.f;
        }
        __syncthreads();
        float4 c0, c1, c2, c3;
        c0 = *(const float4*)&b1s[f0];
        c1 = c0; c2 = c0; c3 = c0;
        for (int k = 0; k < KIN; k++) {
            float4 w = *(const float4*)&w1s[k * 64 + f0];
            float4 hv = *(const float4*)&xT[k][nq * 4];
            c0.x += hv.x * w.x; c0.y += hv.x * w.y; c0.z += hv.x * w.z; c0.w += hv.x * w.w;
            c1.x += hv.y * w.x; c1.y += hv.y * w.y; c1.z += hv.y * w.z; c1.w += hv.y * w.w;
            c2.x += hv.z * w.x; c2.y += hv.z * w.y; c2.z += hv.z * w.z; c2.w += hv.z * w.w;
            c3.x += hv.w * w.x; c3.y += hv.w * w.y; c3.z += hv.w * w.z; c3.w += hv.w * w.w;
        }
        __syncthreads();
        int n0 = nq * 4;
        xT[f0 + 0][n0 + 0] = fmaxf(c0.x, 0.f);
        xT[f0 + 1][n0 + 0] = fmaxf(c0.y, 0.f);
        xT[f0 + 2][n0 + 0] = fmaxf(c0.z, 0.f);
        xT[f0 + 3][n0 + 0] = fmaxf(c0.w, 0.f);
        xT[f0 + 0][n0 + 1] = fmaxf(c1.x, 0.f);
        xT[f0 + 1][n0 + 1] = fmaxf(c1.y, 0.f);
        xT[f0 + 2][n0 + 1] = fmaxf(c1.z, 0.f);
        xT[f0 + 3][n0 + 1] = fmaxf(c1.w, 0.f);
        xT[f0 + 0][n0 + 2] = fmaxf(c2.x, 0.f);
        xT[f0 + 1][n0 + 2] = fmaxf(c2.y, 0.f);
        xT[f0 + 2][n0 + 2] = fmaxf(c2.z, 0.f);
        xT[f0 + 3][n0 + 2] = fmaxf(c2.w, 0.f);
        xT[f0 + 0][n0 + 3] = fmaxf(c3.x, 0.f);
        xT[f0 + 1][n0 + 3] = fmaxf(c3.y, 0.f);
        xT[f0 + 2][n0 + 3] = fmaxf(c3.z, 0.f);
        xT[f0 + 3][n0 + 3] = fmaxf(c3.w, 0.f);
        __syncthreads();
        float4 d0, d1, d2, d3;
        d0 = *(const float4*)&b2s[f0];
        d1 = d0; d2 = d0; d3 = d0;
        for (int k = 0; k < 64; k++) {
            float4 w = *(const float4*)&w2s[k * 64 + f0];
            float4 hv = *(const float4*)&xT[k][nq * 4];
            d0.x += hv.x * w.x; d0.y += hv.x * w.y; d0.z += hv.x * w.z; d0.w += hv.x * w.w;
            d1.x += hv.y * w.x; d1.y += hv.y * w.y; d1.z += hv.y * w.z; d1.w += hv.y * w.w;
            d2.x += hv.z * w.x; d2.y += hv.z * w.y; d2.z += hv.z * w.z; d2.w += hv.z * w.w;
            d3.x += hv.w * w.x; d3.y += hv.w * w.y; d3.z += hv.w * w.z; d3.w += hv.w * w.w;
        }
        int gn0 = base + n0;
        uint2* outr = (uint2*)hout;
        if (gn0 + 0 < N) {
            outr[(size_t)(gn0 + 0) * 16 + f4] = make_uint2(bf16pack2(d0.x, d0.y), bf16pack2(d0.z, d0.w));
            bs0 += d0.x; bs1 += d0.y; bs2 += d0.z; bs3 += d0.w;
            bq0 += d0.x * d0.x; bq1 += d0.y * d0.y; bq2 += d0.z * d0.z; bq3 += d0.w * d0.w;
        }
        if (gn0 + 1 < N) {
            outr[(size_t)(gn0 + 1) * 16 + f4] = make_uint2(bf16pack2(d1.x, d1.y), bf16pack2(d1.z, d1.w));
            bs0 += d1.x; bs1 += d1.y; bs2 += d1.z; bs3 += d1.w;
            bq0 += d1.x * d1.x; bq1 += d1.y * d1.y; bq2 += d1.z * d1.z; bq3 += d1.w * d1.w;
        }
        if (gn0 + 2 < N) {
            outr[(size_t)(gn0 + 2) * 16 + f4] = make_uint2(bf16pack2(d2.x, d2.y), bf16pack2(d2.z, d2.w));
            bs0 += d2.x; bs1 += d2.y; bs2 += d2.z; bs3 += d2.w;
            bq0 += d2.x * d2.x; bq1 += d2.y * d2.y; bq2 += d2.z * d2.z; bq3 += d2.w * d2.w;
        }
        if (gn0 + 3 < N) {
            outr[(size_t)(gn0 + 3) * 16 + f4] = make_uint2(bf16pack2(d3.x, d3.y), bf16pack2(d3.z, d3.w));
            bs0 += d3.x; bs1 += d3.y; bs2 += d3.z; bs3 += d3.w;
            bq0 += d3.x * d3.x; bq1 += d3.y * d3.y; bq2 += d3.z * d3.z; bq3 += d3.w * d3.w;
        }
    }
    __syncthreads();
    xT[nq][f0] = bs0; xT[nq][f0 + 1] = bs1; xT[nq][f0 + 2] = bs2; xT[nq][f0 + 3] = bs3;
    __syncthreads();
    if (t < 64) {
        float S = 0.f;
        for (int q = 0; q < 16; q++) S += xT[q][t];
        atomicAdd(&bnsum[t], S);
    }
    __syncthreads();
    xT[nq][f0] = bq0; xT[nq][f0 + 1] = bq1; xT[nq][f0 + 2] = bq2; xT[nq][f0 + 3] = bq3;
    __syncthreads();
    if (t < 64) {
        float Q = 0.f;
        for (int q = 0; q < 16; q++) Q += xT[q][t];
        atomicAdd(&bnsq[t], Q);
    }
}

// ---- BN apply + mean-pool + output matmul, one block per graph (batch
// sorted -> contiguous node ranges; zero atomics); bf16 h ----
__device__ __forceinline__ int lowb(const int* __restrict__ a, int n, int v) {
    int lo = 0, hi = n;
    while (lo < hi) {
        int m = (lo + hi) >> 1;
        if (a[m] < v) lo = m + 1; else hi = m;
    }
    return lo;
}

__global__ __launch_bounds__(256) void bn_pool_out(
    const unsigned short* __restrict__ h, const int* __restrict__ batch,
    const float* __restrict__ bnsum, const float* __restrict__ bnsq,
    const float* __restrict__ gamma, const float* __restrict__ beta,
    const float* __restrict__ wout, const float* __restrict__ bout,
    float* __restrict__ out, int N) {
    __shared__ float sc[64], sh[64];
    __shared__ float part[4][64];
    __shared__ float gr[64];
    __shared__ int range[2];
    int g = blockIdx.x, t = threadIdx.x;
    if (t < 64) {
        float mu = bnsum[t] / (float)N;
        float var = bnsq[t] / (float)N - mu * mu;
        float s = gamma[t] * rsqrtf(var + 1e-5f);
        sc[t] = s;
        sh[t] = beta[t] - mu * s;
    }
    if (t == 64) range[0] = lowb(batch, N, g);
    if (t == 65) range[1] = lowb(batch, N, g + 1);
    __syncthreads();
    int s0 = range[0], s1 = range[1];
    int col = t & 63, ro = t >> 6;
    float acc = 0.f;
    for (int n = s0 + ro; n < s1; n += 4) {
        float v = __uint_as_float(((unsigned)h[(size_t)n * 64 + col]) << 16);
        acc += fmaxf(v * sc[col] + sh[col], 0.f);
    }
    part[ro][col] = acc;
    __syncthreads();
    if (t < 64) {
        float S = part[0][t] + part[1][t] + part[2][t] + part[3][t];
        float c = (float)(s1 - s0);
        gr[t] = (c > 0.f) ? S / c : 0.f;
    }
    __syncthreads();
    if (t < 64) {
        float a = bout[t];
        for (int f = 0; f < 64; f++) a += gr[f] * wout[f * 64 + t];
        out[g * 64 + t] = a;
    }
}

extern "C" void kernel_launch(void* const* d_in, const int* in_sizes, int n_in,
                              void* d_out, int out_size, void* d_ws, size_t ws_size,
                              hipStream_t stream) {
    const float* x     = (const float*)d_in[0];
    const int*   ei    = (const int*)d_in[1];
    const int*   batch = (const int*)d_in[2];
    const float* w1_0  = (const float*)d_in[3];
    const float* w1_r  = (const float*)d_in[4];
    const float* b1    = (const float*)d_in[5];
    const float* w2    = (const float*)d_in[6];
    const float* b2    = (const float*)d_in[7];
    const float* gamma = (const float*)d_in[8];
    const float* beta  = (const float*)d_in[9];
    const float* wout  = (const float*)d_in[10];
    const float* bout  = (const float*)d_in[11];
    float* out = (float*)d_out;

    const int N = in_sizes[2];      // 100000
    const int E = in_sizes[1] / 2;  // 3200000
    const int NB = (N + 127) >> 7;  // 782 buckets

    // Workspace layout (~56 MB)
    float* bufB = (float*)d_ws;                      // N*64 fp32 (agg out / mlp in)
    float* h3   = bufB + (size_t)N * 64;             // N*3
    int*   cursor  = (int*)(h3 + (size_t)N * 3);     // NBMAX  (zeroed region start)
    float* bnstats = (float*)(cursor + NBMAX);       // 6*64   (zeroed region end)
    int*   rowstart = (int*)(bnstats + 384);         // N
    int*   rowend   = rowstart + N;                  // N
    int*   bucketed = rowend + N;                    // NB*CAP (~14.4 MB)
    unsigned short* hb = (unsigned short*)(bucketed + (size_t)NB * CAP);  // N*64 bf16

    const int* srcv = ei;
    const int* dstv = ei + E;

    hipMemsetAsync(cursor, 0, (NBMAX + 384) * 4, stream);

    // --- CSR build ---
    bucket_scatter<<<(E + CHUNK - 1) / CHUNK, 256, 0, stream>>>(srcv, dstv, cursor, bucketed, E);
    bucket_csr<<<NB, 256, 0, stream>>>(bucketed, cursor, rowstart, rowend, N);

    // --- Layer 0 (kin=3) ---
    agg3<<<(N + 255) / 256, 256, 0, stream>>>(x, rowstart, rowend, bucketed, h3, N);
    mlp_gemm<3><<<782, 256, 0, stream>>>(h3, hb, w1_0, b1, w2, b2,
                                         bnstats, bnstats + 64, N);

    // --- Layer 1 (agg fuses BN0 apply; bf16 gather) ---
    agg64_bn<<<(N + 31) / 32, 256, 0, stream>>>(hb, rowstart, rowend, bucketed,
                                                bnstats, bnstats + 64, gamma, beta,
                                                bufB, N);
    mlp_gemm<64><<<782, 256, 0, stream>>>(bufB, hb, w1_r, b1 + 64, w2 + 4096, b2 + 64,
                                          bnstats + 128, bnstats + 192, N);

    // --- Layer 2 (agg fuses BN1 apply; bf16 gather) ---
    agg64_bn<<<(N + 31) / 32, 256, 0, stream>>>(hb, rowstart, rowend, bucketed,
                                                bnstats + 128, bnstats + 192,
                                                gamma + 64, beta + 64, bufB, N);
    mlp_gemm<64><<<782, 256, 0, stream>>>(bufB, hb, w1_r + 4096, b1 + 128, w2 + 8192, b2 + 128,
                                          bnstats + 256, bnstats + 320, N);

    // --- BN2 apply + pool + output matmul (batch sorted -> no atomics) ---
    bn_pool_out<<<512, 256, 0, stream>>>(hb, batch, bnstats + 256, bnstats + 320,
                                         gamma + 128, beta + 128, wout, bout, out, N);
}

// Round 7
// 405.413 us; speedup vs baseline: 8.1328x; 1.1751x over previous
//
#include <hip/hip_runtime.h>

// GIN encoder: N=100k, E=3.2M, G=512, H=64, L=3.
// Round 7: MLP on matrix cores (mfma_f32_16x16x32_bf16, fp32 accum, bf16 A/B
// straight from global, relu-mid via XOR-swizzled 8KB LDS tile). Weights
// transposed to bf16 [col][k] by a tiny prep kernel. Aggregation outputs bf16
// (ping-pong). bucket_scatter widened to 512 threads (latency-bound at 13.7%
// occupancy in round 6). BN stats from fp32 accumulators (exact mu/sigma).

#define NBMAX 1024
#define CAP 4608
#define CHUNK 8192

typedef __attribute__((ext_vector_type(8))) short bf16x8;
typedef __attribute__((ext_vector_type(4))) float f32x4;

static __device__ __forceinline__ bf16x8 as_bf16x8(uint4 u) {
    union { uint4 a; bf16x8 b; } x; x.a = u; return x.b;
}
static __device__ __forceinline__ unsigned short bf16r(float v) {
    unsigned u = __float_as_uint(v);
    return (unsigned short)((u + 0x7FFFu + ((u >> 16) & 1u)) >> 16);
}
static __device__ __forceinline__ unsigned bf16pack2(float a, float b) {
    return (unsigned)bf16r(a) | ((unsigned)bf16r(b) << 16);
}

// ---- weight prep: bf16, transposed to [col][k] (k contiguous = B-fragment) ----
__global__ void prep_weights(const float* __restrict__ w1_0, const float* __restrict__ w1_r,
                             const float* __restrict__ w2, unsigned short* __restrict__ w1T0,
                             unsigned short* __restrict__ w1T, unsigned short* __restrict__ w2T) {
    int t = blockIdx.x * 256 + threadIdx.x;
    if (t < 64 * 32) {                    // layer0 first linear: [64 col][32 k], k>=3 zero
        int c = t >> 5, k = t & 31;
        w1T0[t] = bf16r(k < 3 ? w1_0[k * 64 + c] : 0.f);
    }
    if (t < 2 * 64 * 64) {                // layers 1-2 first linear
        int l = t >> 12, r = t & 4095, c = r >> 6, k = r & 63;
        w1T[t] = bf16r(w1_r[l * 4096 + k * 64 + c]);
    }
    if (t < 3 * 64 * 64) {                // all second linears
        int l = t >> 12, r = t & 4095, c = r >> 6, k = r & 63;
        w2T[t] = bf16r(w2[l * 4096 + k * 64 + c]);
    }
}

// ---- stage 1: bucketed[b*CAP + r] = src | (dstLocal<<20) ----
__global__ __launch_bounds__(512) void bucket_scatter(
    const int* __restrict__ src, const int* __restrict__ dst,
    int* __restrict__ cursor, int* __restrict__ bucketed, int E) {
    __shared__ int h[NBMAX];
    __shared__ int base[NBMAX];
    int t = threadIdx.x;
    for (int i = t; i < NBMAX; i += 512) h[i] = 0;
    __syncthreads();
    int e0 = blockIdx.x * CHUNK, e1 = min(e0 + CHUNK, E);
    for (int e = e0 + t; e < e1; e += 512) atomicAdd(&h[dst[e] >> 7], 1);
    __syncthreads();
    for (int i = t; i < NBMAX; i += 512) {
        int v = h[i];
        base[i] = v ? atomicAdd(&cursor[i], v) : 0;
        h[i] = 0;
    }
    __syncthreads();
    for (int e = e0 + t; e < e1; e += 512) {
        int d = dst[e];
        int bk = d >> 7;
        int r = base[bk] + atomicAdd(&h[bk], 1);
        if (r < CAP) bucketed[bk * CAP + r] = src[e] | ((d & 127) << 20);
    }
}

// ---- stage 2: per-bucket counting sort -> CSR in place ----
__global__ __launch_bounds__(256) void bucket_csr(
    int* __restrict__ bucketed, const int* __restrict__ bcnt,
    int* __restrict__ rowstart, int* __restrict__ rowend, int N) {
    __shared__ int ein[CAP];
    __shared__ int eout[CAP];
    __shared__ int hist[128];
    __shared__ int base[129];
    int b = blockIdx.x, t = threadIdx.x;
    int s = b * CAP, node0 = b << 7;
    int cnt = min(bcnt[b], CAP);
    if (t < 128) hist[t] = 0;
    __syncthreads();
    for (int j = t; j < cnt; j += 256) {
        int p = bucketed[s + j];
        ein[j] = p;
        atomicAdd(&hist[p >> 20], 1);
    }
    __syncthreads();
    if (t < 128) base[t + 1] = hist[t];
    if (t == 0) base[0] = 0;
    __syncthreads();
    for (int off = 1; off < 128; off <<= 1) {
        int v = 0;
        if (t < 128 && (t + 1) > off) v = base[t + 1 - off];
        __syncthreads();
        if (t < 128 && (t + 1) > off) base[t + 1] += v;
        __syncthreads();
    }
    if (t < 128) {
        int n = node0 + t;
        if (n < N) {
            rowstart[n] = s + base[t];
            rowend[n] = s + base[t + 1];
        }
        hist[t] = 0;
    }
    __syncthreads();
    for (int j = t; j < cnt; j += 256) {
        int p = ein[j];
        int local = p >> 20;
        int pos = base[local] + atomicAdd(&hist[local], 1);
        eout[pos] = p & 0xFFFFF;
    }
    __syncthreads();
    for (int j = t; j < cnt; j += 256) bucketed[s + j] = eout[j];
}

// ---- layer-0 agg (d=3): writes bf16 [n][8] padded rows (uint4/node) ----
__global__ void agg3(const float* __restrict__ x, const int* __restrict__ rowstart,
                     const int* __restrict__ rowend, const int* __restrict__ csr,
                     uint4* __restrict__ out, int N) {
    int n = blockIdx.x * blockDim.x + threadIdx.x;
    if (n >= N) return;
    float a0 = x[n * 3], a1 = x[n * 3 + 1], a2 = x[n * 3 + 2];
    float b0 = 0.f, b1 = 0.f, b2 = 0.f;
    float c0 = 0.f, c1 = 0.f, c2 = 0.f;
    float d0 = 0.f, d1 = 0.f, d2 = 0.f;
    int s = rowstart[n], e = rowend[n];
    int j = s;
    for (; j + 3 < e; j += 4) {
        int i0 = csr[j], i1 = csr[j + 1], i2 = csr[j + 2], i3 = csr[j + 3];
        a0 += x[i0 * 3]; a1 += x[i0 * 3 + 1]; a2 += x[i0 * 3 + 2];
        b0 += x[i1 * 3]; b1 += x[i1 * 3 + 1]; b2 += x[i1 * 3 + 2];
        c0 += x[i2 * 3]; c1 += x[i2 * 3 + 1]; c2 += x[i2 * 3 + 2];
        d0 += x[i3 * 3]; d1 += x[i3 * 3 + 1]; d2 += x[i3 * 3 + 2];
    }
    for (; j < e; j++) {
        int nb = csr[j];
        a0 += x[nb * 3]; a1 += x[nb * 3 + 1]; a2 += x[nb * 3 + 2];
    }
    float s0 = a0 + b0 + c0 + d0, s1 = a1 + b1 + c1 + d1, s2 = a2 + b2 + c2 + d2;
    out[n] = make_uint4(bf16pack2(s0, s1), bf16pack2(s2, 0.f), 0u, 0u);
}

// bf16x2-packed accumulate of relu(v*sc+sh)
__device__ __forceinline__ void accum_bf16(const uint4 u,
                                           const float4 scA, const float4 scB,
                                           const float4 shA, const float4 shB,
                                           float* __restrict__ a) {
    a[0] += fmaxf(__uint_as_float(u.x << 16) * scA.x + shA.x, 0.f);
    a[1] += fmaxf(__uint_as_float(u.x & 0xFFFF0000u) * scA.y + shA.y, 0.f);
    a[2] += fmaxf(__uint_as_float(u.y << 16) * scA.z + shA.z, 0.f);
    a[3] += fmaxf(__uint_as_float(u.y & 0xFFFF0000u) * scA.w + shA.w, 0.f);
    a[4] += fmaxf(__uint_as_float(u.z << 16) * scB.x + shB.x, 0.f);
    a[5] += fmaxf(__uint_as_float(u.z & 0xFFFF0000u) * scB.y + shB.y, 0.f);
    a[6] += fmaxf(__uint_as_float(u.w << 16) * scB.z + shB.z, 0.f);
    a[7] += fmaxf(__uint_as_float(u.w & 0xFFFF0000u) * scB.w + shB.w, 0.f);
}

// ---- layers 1-2 agg + fused BN apply; bf16 in, bf16 out ----
__global__ __launch_bounds__(256) void agg64_bn(
    const unsigned short* __restrict__ h, const int* __restrict__ rowstart,
    const int* __restrict__ rowend, const int* __restrict__ csr,
    const float* __restrict__ bnsum, const float* __restrict__ bnsq,
    const float* __restrict__ gamma, const float* __restrict__ beta,
    uint4* __restrict__ out, int N) {
    __shared__ float scs[64], shs[64];
    int t = threadIdx.x;
    if (t < 64) {
        float mu = bnsum[t] / (float)N;
        float var = bnsq[t] / (float)N - mu * mu;
        float s = gamma[t] * rsqrtf(var + 1e-5f);
        scs[t] = s;
        shs[t] = beta[t] - mu * s;
    }
    __syncthreads();
    int g = t >> 3, l = t & 7;
    int n = blockIdx.x * 32 + g;
    if (n >= N) return;
    int c0 = l * 8;
    float4 scA = *(const float4*)&scs[c0], scB = *(const float4*)&scs[c0 + 4];
    float4 shA = *(const float4*)&shs[c0], shB = *(const float4*)&shs[c0 + 4];
    const uint4* hr = (const uint4*)h;
    float A[8] = {0,0,0,0,0,0,0,0};
    float B[8] = {0,0,0,0,0,0,0,0};
    uint4 self = hr[(size_t)n * 8 + l];
    accum_bf16(self, scA, scB, shA, shB, A);
    int s = rowstart[n], e = rowend[n];
    int j = s;
    for (; j + 3 < e; j += 4) {
        int i0 = csr[j], i1 = csr[j + 1], i2 = csr[j + 2], i3 = csr[j + 3];
        uint4 w0 = hr[(size_t)i0 * 8 + l];
        uint4 w1 = hr[(size_t)i1 * 8 + l];
        uint4 w2 = hr[(size_t)i2 * 8 + l];
        uint4 w3 = hr[(size_t)i3 * 8 + l];
        accum_bf16(w0, scA, scB, shA, shB, A);
        accum_bf16(w1, scA, scB, shA, shB, B);
        accum_bf16(w2, scA, scB, shA, shB, A);
        accum_bf16(w3, scA, scB, shA, shB, B);
    }
    for (; j < e; j++) {
        uint4 w = hr[(size_t)csr[j] * 8 + l];
        accum_bf16(w, scA, scB, shA, shB, A);
    }
    uint4 o;
    o.x = bf16pack2(A[0] + B[0], A[1] + B[1]);
    o.y = bf16pack2(A[2] + B[2], A[3] + B[3]);
    o.z = bf16pack2(A[4] + B[4], A[5] + B[5]);
    o.w = bf16pack2(A[6] + B[6], A[7] + B[7]);
    out[(size_t)n * 8 + l] = o;
}

// ---- MLP on MFMA. Block = 4 waves, 64-node tile. Wave w owns rows w*16..+15.
// A-frags from global bf16, B-frags (wT) from global (L1-hot). relu-mid via
// XOR-swizzled LDS (kblk ^= row&7 -> conflict-free b128 reads). fp32 accum;
// fused BN stats; bf16 output. ----
template <bool L0>
__global__ __launch_bounds__(256) void mlp_mfma(
    const uint4* __restrict__ actIn,           // L0: [n] one u4; else [n][8] u4
    unsigned short* __restrict__ hout,         // [n][64] bf16
    const uint4* __restrict__ w1Tu,            // L0: [col][4]u4; else [col][8]u4
    const float* __restrict__ b1,
    const uint4* __restrict__ w2Tu,            // [col][8]u4
    const float* __restrict__ b2,
    float* __restrict__ bnsum, float* __restrict__ bnsq, int N) {
    __shared__ unsigned short mids[64 * 64];   // swizzled relu-mid (8KB)
    __shared__ float red[16][64];
    int t = threadIdx.x;
    int w = t >> 6, l = t & 63;
    int m16 = l & 15, q = l >> 4;
    float s[4] = {0, 0, 0, 0}, sq[4] = {0, 0, 0, 0};
    const uint4 z4 = make_uint4(0, 0, 0, 0);
    for (int base = blockIdx.x * 64; base < N; base += gridDim.x * 64) {
        __syncthreads();  // mids reuse across iterations
        int rA = base + w * 16 + m16;
        bf16x8 a0, a1;
        if (L0) {
            a0 = as_bf16x8((rA < N && q == 0) ? actIn[rA] : z4);
        } else {
            a0 = as_bf16x8(rA < N ? actIn[(size_t)rA * 8 + q] : z4);
            a1 = as_bf16x8(rA < N ? actIn[(size_t)rA * 8 + 4 + q] : z4);
        }
        for (int c = 0; c < 4; c++) {
            int col = c * 16 + m16;
            float bias = b1[col];
            f32x4 acc = {bias, bias, bias, bias};
            if (L0) {
                bf16x8 bb0 = as_bf16x8(w1Tu[col * 4 + q]);
                acc = __builtin_amdgcn_mfma_f32_16x16x32_bf16(a0, bb0, acc, 0, 0, 0);
            } else {
                bf16x8 bb0 = as_bf16x8(w1Tu[col * 8 + q]);
                bf16x8 bb1 = as_bf16x8(w1Tu[col * 8 + 4 + q]);
                acc = __builtin_amdgcn_mfma_f32_16x16x32_bf16(a0, bb0, acc, 0, 0, 0);
                acc = __builtin_amdgcn_mfma_f32_16x16x32_bf16(a1, bb1, acc, 0, 0, 0);
            }
            int kb = col >> 3, ko = col & 7;
#pragma unroll
            for (int r = 0; r < 4; r++) {
                int row = w * 16 + q * 4 + r;   // C/D: col=lane&15, row=quad*4+reg
                mids[row * 64 + ((kb ^ (row & 7)) << 3) + ko] = bf16r(fmaxf(acc[r], 0.f));
            }
        }
        __syncthreads();
        int rowM = w * 16 + m16;
        const uint4* midU4 = (const uint4*)mids;
        bf16x8 a20 = as_bf16x8(midU4[rowM * 8 + (q ^ (rowM & 7))]);
        bf16x8 a21 = as_bf16x8(midU4[rowM * 8 + ((4 + q) ^ (rowM & 7))]);
        for (int c = 0; c < 4; c++) {
            int col = c * 16 + m16;
            float bias = b2[col];
            f32x4 acc = {bias, bias, bias, bias};
            bf16x8 bb0 = as_bf16x8(w2Tu[col * 8 + q]);
            bf16x8 bb1 = as_bf16x8(w2Tu[col * 8 + 4 + q]);
            acc = __builtin_amdgcn_mfma_f32_16x16x32_bf16(a20, bb0, acc, 0, 0, 0);
            acc = __builtin_amdgcn_mfma_f32_16x16x32_bf16(a21, bb1, acc, 0, 0, 0);
#pragma unroll
            for (int r = 0; r < 4; r++) {
                int row = base + w * 16 + q * 4 + r;
                if (row < N) {
                    float v = acc[r];
                    hout[(size_t)row * 64 + col] = bf16r(v);
                    s[c] += v;
                    sq[c] += v * v;
                }
            }
        }
    }
    __syncthreads();
    for (int c = 0; c < 4; c++) red[w * 4 + q][c * 16 + m16] = s[c];
    __syncthreads();
    if (t < 64) {
        float S = 0.f;
        for (int i = 0; i < 16; i++) S += red[i][t];
        atomicAdd(&bnsum[t], S);
    }
    __syncthreads();
    for (int c = 0; c < 4; c++) red[w * 4 + q][c * 16 + m16] = sq[c];
    __syncthreads();
    if (t < 64) {
        float S = 0.f;
        for (int i = 0; i < 16; i++) S += red[i][t];
        atomicAdd(&bnsq[t], S);
    }
}

// ---- BN apply + mean-pool + output matmul (batch sorted; zero atomics) ----
__device__ __forceinline__ int lowb(const int* __restrict__ a, int n, int v) {
    int lo = 0, hi = n;
    while (lo < hi) {
        int m = (lo + hi) >> 1;
        if (a[m] < v) lo = m + 1; else hi = m;
    }
    return lo;
}

__global__ __launch_bounds__(256) void bn_pool_out(
    const unsigned short* __restrict__ h, const int* __restrict__ batch,
    const float* __restrict__ bnsum, const float* __restrict__ bnsq,
    const float* __restrict__ gamma, const float* __restrict__ beta,
    const float* __restrict__ wout, const float* __restrict__ bout,
    float* __restrict__ out, int N) {
    __shared__ float sc[64], sh[64];
    __shared__ float part[4][64];
    __shared__ float gr[64];
    __shared__ int range[2];
    int g = blockIdx.x, t = threadIdx.x;
    if (t < 64) {
        float mu = bnsum[t] / (float)N;
        float var = bnsq[t] / (float)N - mu * mu;
        float s = gamma[t] * rsqrtf(var + 1e-5f);
        sc[t] = s;
        sh[t] = beta[t] - mu * s;
    }
    if (t == 64) range[0] = lowb(batch, N, g);
    if (t == 65) range[1] = lowb(batch, N, g + 1);
    __syncthreads();
    int s0 = range[0], s1 = range[1];
    int col = t & 63, ro = t >> 6;
    float acc = 0.f;
    for (int n = s0 + ro; n < s1; n += 4) {
        float v = __uint_as_float(((unsigned)h[(size_t)n * 64 + col]) << 16);
        acc += fmaxf(v * sc[col] + sh[col], 0.f);
    }
    part[ro][col] = acc;
    __syncthreads();
    if (t < 64) {
        float S = part[0][t] + part[1][t] + part[2][t] + part[3][t];
        float c = (float)(s1 - s0);
        gr[t] = (c > 0.f) ? S / c : 0.f;
    }
    __syncthreads();
    if (t < 64) {
        float a = bout[t];
        for (int f = 0; f < 64; f++) a += gr[f] * wout[f * 64 + t];
        out[g * 64 + t] = a;
    }
}

extern "C" void kernel_launch(void* const* d_in, const int* in_sizes, int n_in,
                              void* d_out, int out_size, void* d_ws, size_t ws_size,
                              hipStream_t stream) {
    const float* x     = (const float*)d_in[0];
    const int*   ei    = (const int*)d_in[1];
    const int*   batch = (const int*)d_in[2];
    const float* w1_0  = (const float*)d_in[3];
    const float* w1_r  = (const float*)d_in[4];
    const float* b1    = (const float*)d_in[5];
    const float* w2    = (const float*)d_in[6];
    const float* b2    = (const float*)d_in[7];
    const float* gamma = (const float*)d_in[8];
    const float* beta  = (const float*)d_in[9];
    const float* wout  = (const float*)d_in[10];
    const float* bout  = (const float*)d_in[11];
    float* out = (float*)d_out;

    const int N = in_sizes[2];      // 100000
    const int E = in_sizes[1] / 2;  // 3200000
    const int NB = (N + 127) >> 7;  // 782 buckets

    // Workspace layout (~43 MB)
    unsigned short* hbX = (unsigned short*)d_ws;            // N*64 bf16
    unsigned short* hbY = hbX + (size_t)N * 64;             // N*64 bf16
    uint4* h3b = (uint4*)(hbY + (size_t)N * 64);            // N u4 (layer0 act)
    int* bucketed = (int*)(h3b + N);                        // NB*CAP
    int* rowstart = bucketed + (size_t)NB * CAP;            // N
    int* rowend   = rowstart + N;                           // N
    int* cursor   = rowend + N;                             // NBMAX (zero start)
    float* bnstats = (float*)(cursor + NBMAX);              // 6*64  (zero end)
    unsigned short* w1T0 = (unsigned short*)(bnstats + 384);// 64*32
    unsigned short* w1T  = w1T0 + 64 * 32;                  // 2*64*64
    unsigned short* w2T  = w1T + 2 * 64 * 64;               // 3*64*64

    const int* srcv = ei;
    const int* dstv = ei + E;

    hipMemsetAsync(cursor, 0, (NBMAX + 384) * 4, stream);
    prep_weights<<<48, 256, 0, stream>>>(w1_0, w1_r, w2, w1T0, w1T, w2T);

    // --- CSR build ---
    bucket_scatter<<<(E + CHUNK - 1) / CHUNK, 512, 0, stream>>>(srcv, dstv, cursor, bucketed, E);
    bucket_csr<<<NB, 256, 0, stream>>>(bucketed, cursor, rowstart, rowend, N);

    // --- Layer 0 ---
    agg3<<<(N + 255) / 256, 256, 0, stream>>>(x, rowstart, rowend, bucketed, h3b, N);
    mlp_mfma<true><<<782, 256, 0, stream>>>(h3b, hbX, (const uint4*)w1T0, b1,
                                            (const uint4*)w2T, b2,
                                            bnstats, bnstats + 64, N);

    // --- Layer 1 ---
    agg64_bn<<<(N + 31) / 32, 256, 0, stream>>>(hbX, rowstart, rowend, bucketed,
                                                bnstats, bnstats + 64, gamma, beta,
                                                (uint4*)hbY, N);
    mlp_mfma<false><<<782, 256, 0, stream>>>((const uint4*)hbY, hbX, (const uint4*)w1T,
                                             b1 + 64, (const uint4*)(w2T + 4096), b2 + 64,
                                             bnstats + 128, bnstats + 192, N);

    // --- Layer 2 ---
    agg64_bn<<<(N + 31) / 32, 256, 0, stream>>>(hbX, rowstart, rowend, bucketed,
                                                bnstats + 128, bnstats + 192,
                                                gamma + 64, beta + 64, (uint4*)hbY, N);
    mlp_mfma<false><<<782, 256, 0, stream>>>((const uint4*)hbY, hbX,
                                             (const uint4*)(w1T + 4096), b1 + 128,
                                             (const uint4*)(w2T + 8192), b2 + 128,
                                             bnstats + 256, bnstats + 320, N);

    // --- BN2 apply + pool + output matmul ---
    bn_pool_out<<<512, 256, 0, stream>>>(hbX, batch, bnstats + 256, bnstats + 320,
                                         gamma + 128, beta + 128, wout, bout, out, N);
}